// Round 7
// baseline (634.070 us; speedup 1.0000x reference)
//
#include <hip/hip_runtime.h>
#include <stdint.h>

#define DIMD 1024
#define NH 16
#define NKV 4
#define HD 64
#define NEXP 4
#define HID 3072
#define BB 2
#define SS 2048
#define NT (BB*SS)
#define EPSF 1.1920928955078125e-07f
#define LOG2E 1.4426950408889634f

typedef short short8 __attribute__((ext_vector_type(8)));
typedef short short4v __attribute__((ext_vector_type(4)));
typedef float f32x4 __attribute__((ext_vector_type(4)));

__device__ __forceinline__ short f2bf(float f) {
  union { float f; unsigned u; } c; c.f = f;
  unsigned u = c.u;
  unsigned r = u + 0x7fffu + ((u >> 16) & 1u);
  return (short)(r >> 16);
}
__device__ __forceinline__ float bf2f(short s) {
  union { unsigned u; float f; } c;
  c.u = ((unsigned)(unsigned short)s) << 16;
  return c.f;
}
__device__ __forceinline__ float fexp2(float x) {
#if __has_builtin(__builtin_amdgcn_exp2f)
  return __builtin_amdgcn_exp2f(x);
#else
  return exp2f(x);
#endif
}

__device__ __forceinline__ f32x4 mfma16(short8 a, short8 b, f32x4 c) {
  return __builtin_amdgcn_mfma_f32_16x16x32_bf16(a, b, c, 0, 0, 0);
}

#define GLOAD16(gp, lp) __builtin_amdgcn_global_load_lds( \
    (const __attribute__((address_space(1))) void*)(gp),  \
    (__attribute__((address_space(3))) void*)(lp), 16, 0, 0)

// ---------------- transpose + f32->bf16 convert ------------------------------
template<int SPLIT>
__global__ __launch_bounds__(256) void transpose_k(
    const float* __restrict__ in, short* __restrict__ o1, short* __restrict__ o2,
    int Krows, int N, size_t inStride, size_t outStride, int ldo1, int ldo2,
    int mapMode) {
  __shared__ float tile[64][68];
  const float* inp = in + (size_t)blockIdx.z * inStride;
  short* hp = o1 + (size_t)blockIdx.z * outStride;
  short* lp = SPLIT ? (o2 + (size_t)blockIdx.z * outStride) : (short*)0;
  int tx = threadIdx.x & 15, ty = threadIdx.x >> 4;  // 16 x 16
  int n0 = blockIdx.x * 64, k0 = blockIdx.y * 64;
#pragma unroll
  for (int p = 0; p < 4; ++p) {
    int k = p * 16 + ty;
    float4 v = *(const float4*)&inp[(size_t)(k0 + k) * N + n0 + tx * 4];
    *(float4*)&tile[k][tx * 4] = v;
  }
  __syncthreads();
#pragma unroll
  for (int p = 0; p < 4; ++p) {
    int n = n0 + p * 16 + ty;
    int np = mapMode ? ((n >> 4) * 32 + (n & 15) + ((mapMode == 2) ? 16 : 0)) : n;
    int k4 = tx * 4;
    short4v hv, lv;
#pragma unroll
    for (int j = 0; j < 4; ++j) {
      float v = tile[k4 + j][p * 16 + ty];
      short h_ = f2bf(v);
      hv[j] = h_;
      if (SPLIT) lv[j] = f2bf(v - bf2f(h_));
    }
    *(short4v*)&hp[(size_t)np * ldo1 + k0 + k4] = hv;
    if (SPLIT) *(short4v*)&lp[(size_t)np * ldo2 + k0 + k4] = lv;
  }
}

// ---------------- RMSNorm (f32 in -> bf16 out) ------------------------------
__global__ __launch_bounds__(256) void rmsnorm_k(
    const float* __restrict__ x, const float* __restrict__ g, short* __restrict__ outq) {
  int row = blockIdx.x;
  int t = threadIdx.x;
  const float4* xr = (const float4*)(x + (size_t)row * DIMD);
  float4 v = xr[t];
  float ss = v.x*v.x + v.y*v.y + v.z*v.z + v.w*v.w;
#pragma unroll
  for (int off = 1; off < 64; off <<= 1) ss += __shfl_xor(ss, off);
  __shared__ float red[4];
  if ((t & 63) == 0) red[t >> 6] = ss;
  __syncthreads();
  float tot = red[0] + red[1] + red[2] + red[3];
  float scn = rsqrtf(tot * (1.f/1024.f) + EPSF);
  float4 gv = ((const float4*)g)[t];
  short4v ov;
  ov[0] = f2bf(v.x * scn * gv.x);
  ov[1] = f2bf(v.y * scn * gv.y);
  ov[2] = f2bf(v.z * scn * gv.z);
  ov[3] = f2bf(v.w * scn * gv.w);
  ((short4v*)outq)[(size_t)row * 256 + t] = ov;
}

// ---------------- RoPE tables ----------------------------------------------
__global__ __launch_bounds__(256) void rope_tables_k(
    float* __restrict__ cosT, float* __restrict__ sinT) {
  int t = blockIdx.x * 256 + threadIdx.x;  // 2048*32
  int s = t >> 5, i = t & 31;
  float invf = powf(10000.0f, -(float)i / 32.0f);
  float a = (float)s * invf;
  cosT[t] = cosf(a);
  sinT[t] = sinf(a);
}

// ---------------- RoPE apply + scatter to attention layouts -----------------
#define QSCALE 0.18033688011112042f
__global__ __launch_bounds__(256) void rope_scatter_k(
    const float* __restrict__ qkv, const float* __restrict__ cosT,
    const float* __restrict__ sinT, short* __restrict__ Qb,
    short* __restrict__ Kb, short* __restrict__ Vt) {
  int r = blockIdx.x;
  int t = threadIdx.x;
  int b = r >> 11, s = r & 2047;
  __shared__ float row[1536];
  const float* rp = qkv + (size_t)r * 1536;
  for (int i = t; i < 1536; i += 256) row[i] = rp[i];
  __syncthreads();
  const float* cs = cosT + s * 32;
  const float* sn = sinT + s * 32;
  {
    int c = t * 4, hh = c >> 6, j = c & 63;
    short4v ov;
#pragma unroll
    for (int u = 0; u < 4; ++u) {
      int jj = j + u;
      float xv = row[hh*64 + jj];
      float rot = (jj < 32) ? -row[hh*64 + jj + 32] : row[hh*64 + jj - 32];
      ov[u] = f2bf((xv * cs[jj & 31] + rot * sn[jj & 31]) * QSCALE);
    }
    *(short4v*)&Qb[((size_t)(b*NH + hh) * SS + s) * 64 + j] = ov;
  }
  if (t < 64) {
    int c = t * 4, kvh = c >> 6, j = c & 63;
    short4v ov;
#pragma unroll
    for (int u = 0; u < 4; ++u) {
      int jj = j + u;
      float xv = row[1024 + kvh*64 + jj];
      float rot = (jj < 32) ? -row[1024 + kvh*64 + jj + 32] : row[1024 + kvh*64 + jj - 32];
      ov[u] = f2bf(xv * cs[jj & 31] + rot * sn[jj & 31]);
    }
    *(short4v*)&Kb[((size_t)(b*NKV + kvh) * SS + s) * 64 + j] = ov;
  } else if (t < 128) {
    int c = (t - 64) * 4, kvh = c >> 6, j = c & 63;
#pragma unroll
    for (int u = 0; u < 4; ++u)
      Vt[((size_t)(b*NKV + kvh) * 64 + j + u) * SS + s] = f2bf(row[1280 + kvh*64 + j + u]);
  }
}

// ---------------- 128x128 GEMM (single-buffered, proven) --------------------
// EPI: 0 C=v | 1 C=v+R | 6 batched w2: compact rows, atomic scatter |
//      7 batched w13: gather-A by token list, fused SwiGLU -> Cb bf16.
// AFOLD: A k-index folds (k<1024?k:k-1024) for split-precision O-proj.
template<int EPI, int AFOLD>
__global__ __launch_bounds__(256, 2) void gemm_bt(
    const short* __restrict__ A, const short* __restrict__ Bt,
    float* __restrict__ C, short* __restrict__ Cb,
    const float* __restrict__ R,
    const int* __restrict__ idx, const int* __restrict__ meta,
    const float* __restrict__ comb,
    int M, int N, int K, int lda, int ldb) {
  __shared__ short As[128*64];
  __shared__ short Bs[128*64];
  int nx = gridDim.x, ny = gridDim.y;
  int nwg = nx * ny * gridDim.z;
  int o = blockIdx.x + nx * (blockIdx.y + ny * blockIdx.z);
  int xcd = o & 7, loc = o >> 3;
  int q = nwg >> 3, rr = nwg & 7;
  int wg = (xcd < rr ? xcd * (q + 1) : rr * (q + 1) + (xcd - rr) * q) + loc;
  int bm = wg % nx; int t1 = wg / nx; int bn = t1 % ny; int bz = t1 / ny;
  int tid = threadIdx.x;
  int w = tid >> 6, lane = tid & 63;
  int m0 = bm * 128, n0 = bn * 128;
  int cnt = M, abase = 0, eidx = 0, hrow0 = 0;
  const int* list = idx;
  if (EPI == 7) {
    const int* mp = meta + bz * 4;
    cnt = mp[1]; hrow0 = mp[2];
    list = idx + bz * 4096;
    Bt += (size_t)bz * 6144 * ldb;
    if (m0 >= cnt) return;
  }
  if (EPI == 6) {
    eidx = bz >> 1; int slot = bz & 1;
    const int* mp = meta + eidx * 4;
    int cA = mp[0], cT = mp[1];
    cnt = slot ? (cT - cA) : cA;
    abase = mp[2] + (slot ? cA : 0);
    list = idx + eidx * 4096 + (slot ? cA : 0);
    Bt += (size_t)eidx * 1024 * ldb;
    if (m0 >= cnt) return;
  }
  int wr = (w >> 1) * 64, wc = (w & 1) * 64;
  int l15 = lane & 15, lg = lane >> 4;
  int srow = lane >> 3, sslot = lane & 7;
  const short* aptr[4];
  const short* bptr[4];
#pragma unroll
  for (int i = 0; i < 4; ++i) {
    int row = i * 32 + w * 8 + srow;
    int gs = (sslot ^ (row & 7)) * 8;
    int am = m0 + row;
    if (EPI == 7) am = list[am < cnt ? am : cnt - 1];
    else if (EPI == 6) am = abase + am;
    aptr[i] = A + (size_t)am * lda + gs;
    bptr[i] = Bt + (size_t)(n0 + row) * ldb + gs;
  }
  f32x4 acc[4][4] = {};
  int nK = K >> 6;
  for (int kt = 0; kt < nK; ++kt) {
    int k0 = kt << 6;
    int ak0 = AFOLD ? (kt < 16 ? k0 : k0 - 1024) : k0;
    __syncthreads();
#pragma unroll
    for (int i = 0; i < 4; ++i) {
      int r0 = i * 32 + w * 8;
      GLOAD16(aptr[i] + ak0, &As[r0 * 64]);
      GLOAD16(bptr[i] + k0, &Bs[r0 * 64]);
    }
    asm volatile("s_waitcnt vmcnt(0)" ::: "memory");
    __syncthreads();
#pragma unroll
    for (int kh = 0; kh < 2; ++kh) {
      short8 af[4], bfv[4];
#pragma unroll
      for (int mi = 0; mi < 4; ++mi) {
        int row = wr + mi * 16 + l15;
        int sl = (lg + kh * 4) ^ (row & 7);
        af[mi] = *(const short8*)&As[row * 64 + sl * 8];
        int rowb = wc + mi * 16 + l15;
        int slb = (lg + kh * 4) ^ (rowb & 7);
        bfv[mi] = *(const short8*)&Bs[rowb * 64 + slb * 8];
      }
#pragma unroll
      for (int mi = 0; mi < 4; ++mi)
#pragma unroll
        for (int ni = 0; ni < 4; ++ni)
          acc[mi][ni] = mfma16(af[mi], bfv[ni], acc[mi][ni]);
    }
  }
#pragma unroll
  for (int mi = 0; mi < 4; ++mi) {
#pragma unroll
    for (int i = 0; i < 4; ++i) {
      int m = m0 + wr + mi * 16 + 4 * lg + i;
      if (EPI == 7) {
        if (m < cnt) {
          int g0 = (n0 + wc) >> 5;
#pragma unroll
          for (int p = 0; p < 2; ++p) {
            float xg = acc[mi][2*p][i];
            float yg = acc[mi][2*p+1][i];
            float sg = 1.f / (1.f + fexp2(-xg * LOG2E));
            Cb[(size_t)(hrow0 + m) * 3072 + (g0 + p) * 16 + l15] = f2bf(xg * sg * yg);
          }
        }
      } else if (EPI == 6) {
        if (m < cnt) {
          int tok = list[m];
          float wgt = comb[tok * 4 + eidx];
#pragma unroll
          for (int ni = 0; ni < 4; ++ni) {
            int n = n0 + wc + ni * 16 + l15;
            atomicAdd(&C[(size_t)tok * 1024 + n], wgt * acc[mi][ni][i]);
          }
        }
      } else {
#pragma unroll
        for (int ni = 0; ni < 4; ++ni) {
          int n = n0 + wc + ni * 16 + l15;
          size_t cidx = (size_t)m * N + n;
          float v = acc[mi][ni][i];
          if (EPI == 0)      C[cidx] = v;
          else               C[cidx] = v + R[cidx];
        }
      }
    }
  }
}

// ---------------- Flash attention: 4 waves, 1 q-tile, K-prefetch pipeline ---
// No max-tracking (scores bounded, exp2 domain). K for iteration kt+1 is
// issued during iteration kt's exp/P/PV phases (register double-buffer) so
// the QK^T never waits on L2 latency. V issued early within the iteration.
__global__ __launch_bounds__(256, 3) void attn_k(
    const short* __restrict__ Qb, const short* __restrict__ Kb,
    const short* __restrict__ Vt, short* __restrict__ AO2) {
  // XCD-chunked decode, qt fastest within chunk: per-XCD balanced work,
  // neighboring blocks share (b,kvh) K/V for L2 locality.
  int o = blockIdx.x;                       // 1024 blocks
  int wg = (o & 7) * 128 + (o >> 3);
  int qt = wg & 31;
  int hb = wg >> 5;
  int h = hb & 15, b = hb >> 4;
  int tid = threadIdx.x;
  int w = tid >> 6, lane = tid & 63;
  int l15 = lane & 15, lg = lane >> 4;
  int kvh = h >> 2;
  __shared__ short P[4][16 * 72];
  short* Pw = P[w];
  const short* Qp = Qb + (size_t)(b * NH + h) * SS * 64;
  const short* Kp = Kb + (size_t)(b * NKV + kvh) * SS * 64;
  const short* Vp = Vt + (size_t)(b * NKV + kvh) * 64 * SS;
  int qbase = qt * 64 + w * 16;
  int qrow0 = qbase + 4 * lg;
  short8 aq0 = *(const short8*)&Qp[(size_t)(qbase + l15) * 64 + 8 * lg];
  short8 aq1 = *(const short8*)&Qp[(size_t)(qbase + l15) * 64 + 8 * lg + 32];
  f32x4 o4[4] = {};
  float lst[4] = {0.f, 0.f, 0.f, 0.f};
  short8 bkA[2][4], bkB[2][4], bv[2][4];
  // prologue: load K tile for kt=0
#pragma unroll
  for (int kh = 0; kh < 2; ++kh)
#pragma unroll
    for (int ni = 0; ni < 4; ++ni)
      bkA[kh][ni] = *(const short8*)&Kp[(size_t)(ni*16 + l15) * 64 + 8*lg + 32*kh];

#define ATTN_ITER(KT, BKC, BKN)                                                \
  {                                                                            \
    int k0 = (KT) * 64;                                                        \
    f32x4 sc[4] = {};                                                          \
    __builtin_amdgcn_s_setprio(1);                                             \
    _Pragma("unroll")                                                          \
    for (int kh = 0; kh < 2; ++kh)                                             \
      _Pragma("unroll")                                                        \
      for (int ni = 0; ni < 4; ++ni)                                           \
        sc[ni] = mfma16(kh ? aq1 : aq0, BKC[kh][ni], sc[ni]);                  \
    __builtin_amdgcn_s_setprio(0);                                             \
    _Pragma("unroll")                                                          \
    for (int kh = 0; kh < 2; ++kh)                                             \
      _Pragma("unroll")                                                        \
      for (int di = 0; di < 4; ++di)                                           \
        bv[kh][di] = *(const short8*)&Vp[(size_t)(di*16 + l15) * SS + k0 + 8*lg + 32*kh]; \
    int k0n = ((KT) < qt) ? k0 + 64 : k0;                                      \
    _Pragma("unroll")                                                          \
    for (int kh = 0; kh < 2; ++kh)                                             \
      _Pragma("unroll")                                                        \
      for (int ni = 0; ni < 4; ++ni)                                           \
        BKN[kh][ni] = *(const short8*)&Kp[(size_t)(k0n + ni*16 + l15) * 64 + 8*lg + 32*kh]; \
    if ((KT) == qt) {                                                          \
      _Pragma("unroll")                                                        \
      for (int ni = 0; ni < 4; ++ni)                                           \
        _Pragma("unroll")                                                      \
        for (int i = 0; i < 4; ++i)                                            \
          if (k0 + ni*16 + l15 > qrow0 + i) sc[ni][i] = -3.0e38f;              \
    }                                                                          \
    _Pragma("unroll")                                                          \
    for (int i = 0; i < 4; ++i) {                                              \
      float ps = 0.f;                                                          \
      _Pragma("unroll")                                                        \
      for (int ni = 0; ni < 4; ++ni) {                                         \
        float pv = fexp2(sc[ni][i]);                                           \
        sc[ni][i] = pv;                                                        \
        ps += pv;                                                              \
      }                                                                        \
      lst[i] += ps;                                                            \
    }                                                                          \
    _Pragma("unroll")                                                          \
    for (int ni = 0; ni < 4; ++ni)                                             \
      _Pragma("unroll")                                                        \
      for (int i = 0; i < 4; ++i)                                              \
        Pw[(4*lg + i) * 72 + ni*16 + l15] = f2bf(sc[ni][i]);                   \
    __builtin_amdgcn_s_setprio(1);                                             \
    _Pragma("unroll")                                                          \
    for (int kh = 0; kh < 2; ++kh) {                                           \
      short8 ap = *(const short8*)&Pw[l15 * 72 + 8*lg + 32*kh];                \
      _Pragma("unroll")                                                        \
      for (int di = 0; di < 4; ++di)                                           \
        o4[di] = mfma16(ap, bv[kh][di], o4[di]);                               \
    }                                                                          \
    __builtin_amdgcn_s_setprio(0);                                             \
  }

  for (int kt = 0; kt <= qt; kt += 2) {
    ATTN_ITER(kt, bkA, bkB);
    if (kt + 1 <= qt) ATTN_ITER(kt + 1, bkB, bkA);
  }
#undef ATTN_ITER

  float rinv[4];
#pragma unroll
  for (int i = 0; i < 4; ++i) {
    float s = lst[i];
    s += __shfl_xor(s, 1); s += __shfl_xor(s, 2);
    s += __shfl_xor(s, 4); s += __shfl_xor(s, 8);
    rinv[i] = 1.f / s;
  }
#pragma unroll
  for (int di = 0; di < 4; ++di) {
#pragma unroll
    for (int i = 0; i < 4; ++i) {
      float val = o4[di][i] * rinv[i];
      short hi_ = f2bf(val);
      short lo_ = f2bf(val - bf2f(hi_));
      size_t idx = ((size_t)(b * SS + qrow0 + i)) * 2048 + h*64 + di*16 + l15;
      AO2[idx] = hi_;
      AO2[idx + 1024] = lo_;
    }
  }
}

// ---------------- MoE routing (f32, from x1 directly) -----------------------
__global__ __launch_bounds__(64) void routing_k(
    const float* __restrict__ x1, const float* __restrict__ g2,
    const float* __restrict__ gate, float* __restrict__ comb, int* __restrict__ rsel) {
  int row = blockIdx.x;
  int l = threadIdx.x;
  const float* xr = x1 + (size_t)row * 1024;
  float ss = 0.f;
  float lgt[4] = {0.f, 0.f, 0.f, 0.f};
  for (int it = 0; it < 4; ++it) {
    int d0 = it * 256 + l * 4;
    float4 v = *(const float4*)&xr[d0];
    float4 gv = *(const float4*)&g2[d0];
    const float* vp = (const float*)&v;
    const float* gp = (const float*)&gv;
#pragma unroll
    for (int u = 0; u < 4; ++u) {
      float xv = vp[u];
      ss += xv * xv;
      float xg = xv * gp[u];
      float4 gr = *(const float4*)&gate[(size_t)(d0 + u) * 4];
      lgt[0] += xg * gr.x; lgt[1] += xg * gr.y;
      lgt[2] += xg * gr.z; lgt[3] += xg * gr.w;
    }
  }
#pragma unroll
  for (int off = 1; off < 64; off <<= 1) {
    ss += __shfl_xor(ss, off);
#pragma unroll
    for (int e = 0; e < 4; ++e) lgt[e] += __shfl_xor(lgt[e], off);
  }
  if (l == 0) {
    float scn = rsqrtf(ss * (1.f/1024.f) + EPSF);
    float lmax = fmaxf(fmaxf(lgt[0], lgt[1]), fmaxf(lgt[2], lgt[3]));
    float p[4];
#pragma unroll
    for (int e = 0; e < 4; ++e) p[e] = expf(scn * (lgt[e] - lmax));
    int i1 = 0;
    for (int e = 1; e < 4; ++e) if (p[e] > p[i1]) i1 = e;
    int i2 = (i1 == 0) ? 1 : 0;
    for (int e = 0; e < 4; ++e) if (e != i1 && p[e] > p[i2]) i2 = e;
    float wsum = p[i1] + p[i2];
    float4 ov = {0.f, 0.f, 0.f, 0.f};
    ((float*)&ov)[i1] = p[i1] / wsum;
    ((float*)&ov)[i2] = p[i2] / wsum;
    *(float4*)&comb[(size_t)row * 4] = ov;
    rsel[row] = i1 * 4 + i2;
  }
}

// ---- per-expert compaction: slot0 (top-1) list then slot1 (top-2) list -----
__global__ __launch_bounds__(1024) void compact_k(
    const int* __restrict__ rsel, int* __restrict__ idxb, int* __restrict__ meta) {
  int e = blockIdx.x;
  int t = threadIdx.x;
  int lane = t & 63, wid = t >> 6;
  int base = t * 4;
  int r[4];
#pragma unroll
  for (int j = 0; j < 4; ++j) r[j] = rsel[base + j];
  __shared__ int wsum[16], woff[16], totA;
  int outb = e * 4096;
#pragma unroll
  for (int pass = 0; pass < 2; ++pass) {
    int loc[4], c = 0;
#pragma unroll
    for (int j = 0; j < 4; ++j) {
      int sel = pass ? (r[j] & 3) : (r[j] >> 2);
      loc[j] = (sel == e) ? 1 : 0;
      c += loc[j];
    }
    int v = c;
#pragma unroll
    for (int off = 1; off < 64; off <<= 1) {
      int o = __shfl_up(v, off);
      if (lane >= off) v += o;
    }
    if (lane == 63) wsum[wid] = v;
    __syncthreads();
    if (t < 16) {
      int s = wsum[t];
      int vv = s;
#pragma unroll
      for (int off = 1; off < 16; off <<= 1) {
        int o = __shfl_up(vv, off);
        if (t >= off) vv += o;
      }
      woff[t] = vv - s;
      if (t == 15) {
        if (pass == 0) { totA = vv; meta[e * 4 + 0] = vv; }
        else           { meta[e * 4 + 1] = totA + vv; }
      }
    }
    __syncthreads();
    int pbase = (pass ? totA : 0) + woff[wid] + (v - c);
#pragma unroll
    for (int j = 0; j < 4; ++j)
      if (loc[j]) idxb[outb + pbase++] = base + j;
    __syncthreads();
  }
}

__global__ void eoff_k(int* __restrict__ meta) {
  if (threadIdx.x == 0 && blockIdx.x == 0) {
    int run = 0;
    for (int e = 0; e < 4; ++e) { meta[e * 4 + 2] = run; run += meta[e * 4 + 1]; }
  }
}

// ---------------- launch ----------------------------------------------------
extern "C" void kernel_launch(void* const* d_in, const int* in_sizes, int n_in,
                              void* d_out, int out_size, void* d_ws, size_t ws_size,
                              hipStream_t stream) {
  const float* x    = (const float*)d_in[0];
  const float* g1   = (const float*)d_in[1];
  const float* g2   = (const float*)d_in[2];
  const float* wq   = (const float*)d_in[3];
  const float* wk   = (const float*)d_in[4];
  const float* wv   = (const float*)d_in[5];
  const float* wo   = (const float*)d_in[6];
  const float* gate = (const float*)d_in[7];
  const float* w1   = (const float*)d_in[8];
  const float* w2   = (const float*)d_in[9];
  const float* w3   = (const float*)d_in[10];
  float* out = (float*)d_out;

  char* p = (char*)d_ws;
  size_t off = 0;
  auto carve = [&](size_t bytes) {
    void* r = p + off;
    off = (off + bytes + 255) & ~(size_t)255;
    return r;
  };
  short* wqkvT = (short*)carve((size_t)1536 * 1024 * 2);
  short* woC3  = (short*)carve((size_t)1024 * 3072 * 2);
  short* w13T  = (short*)carve((size_t)NEXP * 6144 * 1024 * 2);
  short* w2T   = (short*)carve((size_t)NEXP * 1024 * 3072 * 2);
  short* xn1   = (short*)carve((size_t)NT * DIMD * 2);
  short* xn2   = (short*)carve((size_t)NT * DIMD * 2);
  float* qkv   = (float*)carve((size_t)NT * 1536 * 4);
  float* cosT  = (float*)carve((size_t)SS * 32 * 4);
  float* sinT  = (float*)carve((size_t)SS * 32 * 4);
  short* Qb    = (short*)carve((size_t)BB * NH * SS * HD * 2);
  short* Kb    = (short*)carve((size_t)BB * NKV * SS * HD * 2);
  short* Vt    = (short*)carve((size_t)BB * NKV * HD * SS * 2);
  short* AO2   = (short*)carve((size_t)NT * 2048 * 2);
  float* comb  = (float*)carve((size_t)NT * 4 * 4);
  int*   rsel  = (int*)carve((size_t)NT * 4);
  int*   idxb  = (int*)carve((size_t)NEXP * 4096 * 4);
  int*   meta  = (int*)carve((size_t)16 * 4);
  short* Hb    = (short*)carve((size_t)(2 * NT + 256) * 3072 * 2);
  (void)ws_size; (void)in_sizes; (void)n_in; (void)out_size;

  dim3 blk(256);
  // weight prep
  transpose_k<0><<<dim3(16, 16), blk, 0, stream>>>(wq, wqkvT, (short*)0, 1024, 1024, 0, 0, 1024, 0, 0);
  transpose_k<0><<<dim3(4, 16), blk, 0, stream>>>(wk, wqkvT + (size_t)1024 * 1024, (short*)0, 1024, 256, 0, 0, 1024, 0, 0);
  transpose_k<0><<<dim3(4, 16), blk, 0, stream>>>(wv, wqkvT + (size_t)1280 * 1024, (short*)0, 1024, 256, 0, 0, 1024, 0, 0);
  // woC3 [1024][3072] = [Whi | Wlo | Whi]
  transpose_k<1><<<dim3(16, 16), blk, 0, stream>>>(wo, woC3, woC3 + 1024, 1024, 1024, 0, 0, 3072, 3072, 0);
  transpose_k<0><<<dim3(16, 16), blk, 0, stream>>>(wo, woC3 + 2048, (short*)0, 1024, 1024, 0, 0, 3072, 0, 0);
  // w1/w3 interleaved at 16-col granularity into w13T [E][6144][1024]
  transpose_k<0><<<dim3(48, 16, 4), blk, 0, stream>>>(w1, w13T, (short*)0, 1024, 3072, (size_t)1024*3072, (size_t)6144*1024, 1024, 0, 1);
  transpose_k<0><<<dim3(48, 16, 4), blk, 0, stream>>>(w3, w13T, (short*)0, 1024, 3072, (size_t)1024*3072, (size_t)6144*1024, 1024, 0, 2);
  transpose_k<0><<<dim3(16, 48, 4), blk, 0, stream>>>(w2, w2T, (short*)0, 3072, 1024, (size_t)3072*1024, (size_t)1024*3072, 3072, 0, 0);
  rope_tables_k<<<dim3(256), blk, 0, stream>>>(cosT, sinT);

  // attention
  rmsnorm_k<<<dim3(NT), blk, 0, stream>>>(x, g1, xn1);
  gemm_bt<0,0><<<dim3(32, 12), blk, 0, stream>>>(xn1, wqkvT, qkv, (short*)0, (const float*)0,
      (const int*)0, (const int*)0, (const float*)0, NT, 1536, 1024, 1024, 1024);
  rope_scatter_k<<<dim3(NT), blk, 0, stream>>>(qkv, cosT, sinT, Qb, Kb, Vt);
  attn_k<<<dim3(1024), blk, 0, stream>>>(Qb, Kb, Vt, AO2);
  // O-projection split precision in ONE GEMM: K=3072, A=[hi|hi|lo] via fold,
  // B=[Whi|Wlo|Whi]; +x residual.
  gemm_bt<1,1><<<dim3(32, 8), blk, 0, stream>>>(AO2, woC3, out, (short*)0, x,
      (const int*)0, (const int*)0, (const float*)0, NT, 1024, 3072, 2048, 3072);

  // MoE
  rmsnorm_k<<<dim3(NT), blk, 0, stream>>>(out, g2, xn2);
  routing_k<<<dim3(NT), dim3(64), 0, stream>>>(out, g2, gate, comb, rsel);
  compact_k<<<dim3(4), dim3(1024), 0, stream>>>(rsel, idxb, meta);
  eoff_k<<<dim3(1), dim3(64), 0, stream>>>(meta);
  // all experts in one dispatch: 128^2 gather-GEMM + fused SwiGLU -> Hb
  gemm_bt<7,0><<<dim3(32, 48, 4), blk, 0, stream>>>(xn2, w13T, (float*)0, Hb, (const float*)0,
      idxb, meta, (const float*)0, NT, 6144, 1024, 1024, 1024);
  // w2 scatter-accumulate, both slots in one dispatch (atomicAdd f32)
  gemm_bt<6,0><<<dim3(32, 8, 8), blk, 0, stream>>>(Hb, w2T, out, (short*)0, (const float*)0,
      idxb, meta, comb, NT, 1024, 3072, 3072, 3072);
}

// Round 8
// 478.043 us; speedup vs baseline: 1.3264x; 1.3264x over previous
//
#include <hip/hip_runtime.h>
#include <stdint.h>

#define DIMD 1024
#define NH 16
#define NKV 4
#define HD 64
#define NEXP 4
#define HID 3072
#define BB 2
#define SS 2048
#define NT (BB*SS)
#define EPSF 1.1920928955078125e-07f
#define LOG2E 1.4426950408889634f

typedef short short8 __attribute__((ext_vector_type(8)));
typedef short short4v __attribute__((ext_vector_type(4)));
typedef float f32x4 __attribute__((ext_vector_type(4)));

__device__ __forceinline__ short f2bf(float f) {
  union { float f; unsigned u; } c; c.f = f;
  unsigned u = c.u;
  unsigned r = u + 0x7fffu + ((u >> 16) & 1u);
  return (short)(r >> 16);
}
__device__ __forceinline__ float bf2f(short s) {
  union { unsigned u; float f; } c;
  c.u = ((unsigned)(unsigned short)s) << 16;
  return c.f;
}
__device__ __forceinline__ float fexp2(float x) {
#if __has_builtin(__builtin_amdgcn_exp2f)
  return __builtin_amdgcn_exp2f(x);
#else
  return exp2f(x);
#endif
}

__device__ __forceinline__ f32x4 mfma16(short8 a, short8 b, f32x4 c) {
  return __builtin_amdgcn_mfma_f32_16x16x32_bf16(a, b, c, 0, 0, 0);
}

#define GLOAD16(gp, lp) __builtin_amdgcn_global_load_lds( \
    (const __attribute__((address_space(1))) void*)(gp),  \
    (__attribute__((address_space(3))) void*)(lp), 16, 0, 0)

// ---------------- transpose + f32->bf16 convert ------------------------------
template<int SPLIT>
__global__ __launch_bounds__(256) void transpose_k(
    const float* __restrict__ in, short* __restrict__ o1, short* __restrict__ o2,
    int Krows, int N, size_t inStride, size_t outStride, int ldo1, int ldo2,
    int mapMode) {
  __shared__ float tile[64][68];
  const float* inp = in + (size_t)blockIdx.z * inStride;
  short* hp = o1 + (size_t)blockIdx.z * outStride;
  short* lp = SPLIT ? (o2 + (size_t)blockIdx.z * outStride) : (short*)0;
  int tx = threadIdx.x & 15, ty = threadIdx.x >> 4;  // 16 x 16
  int n0 = blockIdx.x * 64, k0 = blockIdx.y * 64;
#pragma unroll
  for (int p = 0; p < 4; ++p) {
    int k = p * 16 + ty;
    float4 v = *(const float4*)&inp[(size_t)(k0 + k) * N + n0 + tx * 4];
    *(float4*)&tile[k][tx * 4] = v;
  }
  __syncthreads();
#pragma unroll
  for (int p = 0; p < 4; ++p) {
    int n = n0 + p * 16 + ty;
    int np = mapMode ? ((n >> 4) * 32 + (n & 15) + ((mapMode == 2) ? 16 : 0)) : n;
    int k4 = tx * 4;
    short4v hv, lv;
#pragma unroll
    for (int j = 0; j < 4; ++j) {
      float v = tile[k4 + j][p * 16 + ty];
      short h_ = f2bf(v);
      hv[j] = h_;
      if (SPLIT) lv[j] = f2bf(v - bf2f(h_));
    }
    *(short4v*)&hp[(size_t)np * ldo1 + k0 + k4] = hv;
    if (SPLIT) *(short4v*)&lp[(size_t)np * ldo2 + k0 + k4] = lv;
  }
}

// ---------------- RMSNorm (f32 in -> bf16 out) ------------------------------
__global__ __launch_bounds__(256) void rmsnorm_k(
    const float* __restrict__ x, const float* __restrict__ g, short* __restrict__ outq) {
  int row = blockIdx.x;
  int t = threadIdx.x;
  const float4* xr = (const float4*)(x + (size_t)row * DIMD);
  float4 v = xr[t];
  float ss = v.x*v.x + v.y*v.y + v.z*v.z + v.w*v.w;
#pragma unroll
  for (int off = 1; off < 64; off <<= 1) ss += __shfl_xor(ss, off);
  __shared__ float red[4];
  if ((t & 63) == 0) red[t >> 6] = ss;
  __syncthreads();
  float tot = red[0] + red[1] + red[2] + red[3];
  float scn = rsqrtf(tot * (1.f/1024.f) + EPSF);
  float4 gv = ((const float4*)g)[t];
  short4v ov;
  ov[0] = f2bf(v.x * scn * gv.x);
  ov[1] = f2bf(v.y * scn * gv.y);
  ov[2] = f2bf(v.z * scn * gv.z);
  ov[3] = f2bf(v.w * scn * gv.w);
  ((short4v*)outq)[(size_t)row * 256 + t] = ov;
}

// ---------------- RoPE tables ----------------------------------------------
__global__ __launch_bounds__(256) void rope_tables_k(
    float* __restrict__ cosT, float* __restrict__ sinT) {
  int t = blockIdx.x * 256 + threadIdx.x;  // 2048*32
  int s = t >> 5, i = t & 31;
  float invf = powf(10000.0f, -(float)i / 32.0f);
  float a = (float)s * invf;
  cosT[t] = cosf(a);
  sinT[t] = sinf(a);
}

// ---------------- RoPE apply + scatter to attention layouts -----------------
#define QSCALE 0.18033688011112042f
__global__ __launch_bounds__(256) void rope_scatter_k(
    const float* __restrict__ qkv, const float* __restrict__ cosT,
    const float* __restrict__ sinT, short* __restrict__ Qb,
    short* __restrict__ Kb, short* __restrict__ Vt) {
  int r = blockIdx.x;
  int t = threadIdx.x;
  int b = r >> 11, s = r & 2047;
  __shared__ float row[1536];
  const float* rp = qkv + (size_t)r * 1536;
  for (int i = t; i < 1536; i += 256) row[i] = rp[i];
  __syncthreads();
  const float* cs = cosT + s * 32;
  const float* sn = sinT + s * 32;
  {
    int c = t * 4, hh = c >> 6, j = c & 63;
    short4v ov;
#pragma unroll
    for (int u = 0; u < 4; ++u) {
      int jj = j + u;
      float xv = row[hh*64 + jj];
      float rot = (jj < 32) ? -row[hh*64 + jj + 32] : row[hh*64 + jj - 32];
      ov[u] = f2bf((xv * cs[jj & 31] + rot * sn[jj & 31]) * QSCALE);
    }
    *(short4v*)&Qb[((size_t)(b*NH + hh) * SS + s) * 64 + j] = ov;
  }
  if (t < 64) {
    int c = t * 4, kvh = c >> 6, j = c & 63;
    short4v ov;
#pragma unroll
    for (int u = 0; u < 4; ++u) {
      int jj = j + u;
      float xv = row[1024 + kvh*64 + jj];
      float rot = (jj < 32) ? -row[1024 + kvh*64 + jj + 32] : row[1024 + kvh*64 + jj - 32];
      ov[u] = f2bf(xv * cs[jj & 31] + rot * sn[jj & 31]);
    }
    *(short4v*)&Kb[((size_t)(b*NKV + kvh) * SS + s) * 64 + j] = ov;
  } else if (t < 128) {
    int c = (t - 64) * 4, kvh = c >> 6, j = c & 63;
#pragma unroll
    for (int u = 0; u < 4; ++u)
      Vt[((size_t)(b*NKV + kvh) * 64 + j + u) * SS + s] = f2bf(row[1280 + kvh*64 + j + u]);
  }
}

// ---------------- 128x128 GEMM (single-buffered, proven) --------------------
// EPI: 0 C=v | 1 C=v+R | 6 batched w2: compact rows, atomic scatter |
//      7 batched w13: gather-A by token list, fused SwiGLU -> Cb bf16.
// AFOLD: A k-index folds (k<1024?k:k-1024) for split-precision O-proj.
template<int EPI, int AFOLD>
__global__ __launch_bounds__(256, 2) void gemm_bt(
    const short* __restrict__ A, const short* __restrict__ Bt,
    float* __restrict__ C, short* __restrict__ Cb,
    const float* __restrict__ R,
    const int* __restrict__ idx, const int* __restrict__ meta,
    const float* __restrict__ comb,
    int M, int N, int K, int lda, int ldb) {
  __shared__ short As[128*64];
  __shared__ short Bs[128*64];
  int nx = gridDim.x, ny = gridDim.y;
  int nwg = nx * ny * gridDim.z;
  int o = blockIdx.x + nx * (blockIdx.y + ny * blockIdx.z);
  int xcd = o & 7, loc = o >> 3;
  int q = nwg >> 3, rr = nwg & 7;
  int wg = (xcd < rr ? xcd * (q + 1) : rr * (q + 1) + (xcd - rr) * q) + loc;
  int bm = wg % nx; int t1 = wg / nx; int bn = t1 % ny; int bz = t1 / ny;
  int tid = threadIdx.x;
  int w = tid >> 6, lane = tid & 63;
  int m0 = bm * 128, n0 = bn * 128;
  int cnt = M, abase = 0, eidx = 0, hrow0 = 0;
  const int* list = idx;
  if (EPI == 7) {
    const int* mp = meta + bz * 4;
    cnt = mp[1]; hrow0 = mp[2];
    list = idx + bz * 4096;
    Bt += (size_t)bz * 6144 * ldb;
    if (m0 >= cnt) return;
  }
  if (EPI == 6) {
    eidx = bz >> 1; int slot = bz & 1;
    const int* mp = meta + eidx * 4;
    int cA = mp[0], cT = mp[1];
    cnt = slot ? (cT - cA) : cA;
    abase = mp[2] + (slot ? cA : 0);
    list = idx + eidx * 4096 + (slot ? cA : 0);
    Bt += (size_t)eidx * 1024 * ldb;
    if (m0 >= cnt) return;
  }
  int wr = (w >> 1) * 64, wc = (w & 1) * 64;
  int l15 = lane & 15, lg = lane >> 4;
  int srow = lane >> 3, sslot = lane & 7;
  const short* aptr[4];
  const short* bptr[4];
#pragma unroll
  for (int i = 0; i < 4; ++i) {
    int row = i * 32 + w * 8 + srow;
    int gs = (sslot ^ (row & 7)) * 8;
    int am = m0 + row;
    if (EPI == 7) am = list[am < cnt ? am : cnt - 1];
    else if (EPI == 6) am = abase + am;
    aptr[i] = A + (size_t)am * lda + gs;
    bptr[i] = Bt + (size_t)(n0 + row) * ldb + gs;
  }
  f32x4 acc[4][4] = {};
  int nK = K >> 6;
  for (int kt = 0; kt < nK; ++kt) {
    int k0 = kt << 6;
    int ak0 = AFOLD ? (kt < 16 ? k0 : k0 - 1024) : k0;
    __syncthreads();
#pragma unroll
    for (int i = 0; i < 4; ++i) {
      int r0 = i * 32 + w * 8;
      GLOAD16(aptr[i] + ak0, &As[r0 * 64]);
      GLOAD16(bptr[i] + k0, &Bs[r0 * 64]);
    }
    asm volatile("s_waitcnt vmcnt(0)" ::: "memory");
    __syncthreads();
#pragma unroll
    for (int kh = 0; kh < 2; ++kh) {
      short8 af[4], bfv[4];
#pragma unroll
      for (int mi = 0; mi < 4; ++mi) {
        int row = wr + mi * 16 + l15;
        int sl = (lg + kh * 4) ^ (row & 7);
        af[mi] = *(const short8*)&As[row * 64 + sl * 8];
        int rowb = wc + mi * 16 + l15;
        int slb = (lg + kh * 4) ^ (rowb & 7);
        bfv[mi] = *(const short8*)&Bs[rowb * 64 + slb * 8];
      }
#pragma unroll
      for (int mi = 0; mi < 4; ++mi)
#pragma unroll
        for (int ni = 0; ni < 4; ++ni)
          acc[mi][ni] = mfma16(af[mi], bfv[ni], acc[mi][ni]);
    }
  }
#pragma unroll
  for (int mi = 0; mi < 4; ++mi) {
#pragma unroll
    for (int i = 0; i < 4; ++i) {
      int m = m0 + wr + mi * 16 + 4 * lg + i;
      if (EPI == 7) {
        if (m < cnt) {
          int g0 = (n0 + wc) >> 5;
#pragma unroll
          for (int p = 0; p < 2; ++p) {
            float xg = acc[mi][2*p][i];
            float yg = acc[mi][2*p+1][i];
            float sg = 1.f / (1.f + fexp2(-xg * LOG2E));
            Cb[(size_t)(hrow0 + m) * 3072 + (g0 + p) * 16 + l15] = f2bf(xg * sg * yg);
          }
        }
      } else if (EPI == 6) {
        if (m < cnt) {
          int tok = list[m];
          float wgt = comb[tok * 4 + eidx];
#pragma unroll
          for (int ni = 0; ni < 4; ++ni) {
            int n = n0 + wc + ni * 16 + l15;
            atomicAdd(&C[(size_t)tok * 1024 + n], wgt * acc[mi][ni][i]);
          }
        }
      } else {
#pragma unroll
        for (int ni = 0; ni < 4; ++ni) {
          int n = n0 + wc + ni * 16 + l15;
          size_t cidx = (size_t)m * N + n;
          float v = acc[mi][ni][i];
          if (EPI == 0)      C[cidx] = v;
          else               C[cidx] = v + R[cidx];
        }
      }
    }
  }
}

// ---------------- Flash attention: 8 waves, two q-tiles, LDS-shared K/V -----
// waves 0-3 -> tile qp, waves 4-7 -> tile 31-qp. K/V tiles staged ONCE per
// block in LDS (global_load_lds, swizzled) and shared by all 8 waves --
// removes the 8x duplicated L2 reads of the per-wave-load version.
// No max-tracking (scores bounded; exp2 domain; softmax shift-invariant).
__global__ __launch_bounds__(512) void attn_k(
    const short* __restrict__ Qb, const short* __restrict__ Kb,
    const short* __restrict__ Vt, short* __restrict__ AO2) {
  int id = blockIdx.x;
  int qp = ((id & 15) + ((id >> 8) << 3)) & 15;
  int hb = (id >> 4) & 31;
  int h = hb & 15, b = hb >> 4;
  int tid = threadIdx.x;
  int w = tid >> 6, lane = tid & 63;
  int half = w >> 2, w4 = w & 3;
  int l15 = lane & 15, lg = lane >> 4;
  int kvh = h >> 2;
  __shared__ short Ks[64 * 64];
  __shared__ short Vs[64 * 64];
  __shared__ short P[8][16 * 72];
  short* Pw = P[w];
  const short* Qp = Qb + (size_t)(b * NH + h) * SS * 64;
  const short* Kp = Kb + (size_t)(b * NKV + kvh) * SS * 64;
  const short* Vp = Vt + (size_t)(b * NKV + kvh) * 64 * SS;
  int qt = half ? (31 - qp) : qp;
  int kmax = 31 - qp;                      // = max(qp, 31-qp) since qp<16
  int qbase = qt * 64 + w4 * 16;
  int qrow0 = qbase + 4 * lg;
  short8 aq0 = *(const short8*)&Qp[(size_t)(qbase + l15) * 64 + 8 * lg];
  short8 aq1 = *(const short8*)&Qp[(size_t)(qbase + l15) * 64 + 8 * lg + 32];
  // staging addresses: row = w*8 + (lane>>3); pre-swizzled global source,
  // linear LDS dest (wave-uniform base + lane*16B)
  int srow = lane >> 3, sslot = lane & 7;
  int strow = w * 8 + srow;                // 0..63
  int sgs = (sslot ^ (strow & 7)) * 8;
  const short* ksrc = Kp + (size_t)strow * 64 + sgs;   // += k0*64 per iter
  const short* vsrc = Vp + (size_t)strow * SS + sgs;   // += k0 per iter
  f32x4 o4[4] = {};
  float lst[4] = {0.f, 0.f, 0.f, 0.f};
  for (int kt = 0; kt <= kmax; ++kt) {
    int k0 = kt * 64;
    __syncthreads();
    GLOAD16(ksrc + (size_t)k0 * 64, &Ks[(w * 8) * 64]);
    GLOAD16(vsrc + k0, &Vs[(w * 8) * 64]);
    asm volatile("s_waitcnt vmcnt(0)" ::: "memory");
    __syncthreads();
    if (kt <= qt) {
      // QK^T: B-frags from swizzled Ks
      f32x4 sc[4] = {};
      short8 bk[2][4];
#pragma unroll
      for (int kh = 0; kh < 2; ++kh)
#pragma unroll
        for (int ni = 0; ni < 4; ++ni) {
          int row = ni * 16 + l15;
          int sl = (lg + kh * 4) ^ (row & 7);
          bk[kh][ni] = *(const short8*)&Ks[row * 64 + sl * 8];
        }
      __builtin_amdgcn_s_setprio(1);
#pragma unroll
      for (int kh = 0; kh < 2; ++kh)
#pragma unroll
        for (int ni = 0; ni < 4; ++ni)
          sc[ni] = mfma16(kh ? aq1 : aq0, bk[kh][ni], sc[ni]);
      __builtin_amdgcn_s_setprio(0);
      // V frags read early (LDS latency hides under exp work)
      short8 bv[2][4];
#pragma unroll
      for (int kh = 0; kh < 2; ++kh)
#pragma unroll
        for (int di = 0; di < 4; ++di) {
          int row = di * 16 + l15;
          int sl = (lg + kh * 4) ^ (row & 7);
          bv[kh][di] = *(const short8*)&Vs[row * 64 + sl * 8];
        }
      if (kt == qt) {
#pragma unroll
        for (int ni = 0; ni < 4; ++ni)
#pragma unroll
          for (int i = 0; i < 4; ++i)
            if (k0 + ni*16 + l15 > qrow0 + i) sc[ni][i] = -3.0e38f;
      }
#pragma unroll
      for (int i = 0; i < 4; ++i) {
        float ps = 0.f;
#pragma unroll
        for (int ni = 0; ni < 4; ++ni) {
          float pv = fexp2(sc[ni][i]);   // masked -> exp2(-3e38) = +0
          sc[ni][i] = pv;
          ps += pv;
        }
        lst[i] += ps;                    // per-lane partial; reduced at end
      }
#pragma unroll
      for (int ni = 0; ni < 4; ++ni)
#pragma unroll
        for (int i = 0; i < 4; ++i)
          Pw[(4*lg + i) * 72 + ni*16 + l15] = f2bf(sc[ni][i]);
      __builtin_amdgcn_s_setprio(1);
#pragma unroll
      for (int kh = 0; kh < 2; ++kh) {
        short8 ap = *(const short8*)&Pw[l15 * 72 + 8*lg + 32*kh];
#pragma unroll
        for (int di = 0; di < 4; ++di)
          o4[di] = mfma16(ap, bv[kh][di], o4[di]);
      }
      __builtin_amdgcn_s_setprio(0);
    }
  }
  float rinv[4];
#pragma unroll
  for (int i = 0; i < 4; ++i) {
    float s = lst[i];
    s += __shfl_xor(s, 1); s += __shfl_xor(s, 2);
    s += __shfl_xor(s, 4); s += __shfl_xor(s, 8);
    rinv[i] = 1.f / s;
  }
#pragma unroll
  for (int di = 0; di < 4; ++di) {
#pragma unroll
    for (int i = 0; i < 4; ++i) {
      float val = o4[di][i] * rinv[i];
      short hi_ = f2bf(val);
      short lo_ = f2bf(val - bf2f(hi_));
      size_t idx = ((size_t)(b * SS + qrow0 + i)) * 2048 + h*64 + di*16 + l15;
      AO2[idx] = hi_;
      AO2[idx + 1024] = lo_;
    }
  }
}

// ---------------- MoE routing (f32, from x1 directly) -----------------------
__global__ __launch_bounds__(64) void routing_k(
    const float* __restrict__ x1, const float* __restrict__ g2,
    const float* __restrict__ gate, float* __restrict__ comb, int* __restrict__ rsel) {
  int row = blockIdx.x;
  int l = threadIdx.x;
  const float* xr = x1 + (size_t)row * 1024;
  float ss = 0.f;
  float lgt[4] = {0.f, 0.f, 0.f, 0.f};
  for (int it = 0; it < 4; ++it) {
    int d0 = it * 256 + l * 4;
    float4 v = *(const float4*)&xr[d0];
    float4 gv = *(const float4*)&g2[d0];
    const float* vp = (const float*)&v;
    const float* gp = (const float*)&gv;
#pragma unroll
    for (int u = 0; u < 4; ++u) {
      float xv = vp[u];
      ss += xv * xv;
      float xg = xv * gp[u];
      float4 gr = *(const float4*)&gate[(size_t)(d0 + u) * 4];
      lgt[0] += xg * gr.x; lgt[1] += xg * gr.y;
      lgt[2] += xg * gr.z; lgt[3] += xg * gr.w;
    }
  }
#pragma unroll
  for (int off = 1; off < 64; off <<= 1) {
    ss += __shfl_xor(ss, off);
#pragma unroll
    for (int e = 0; e < 4; ++e) lgt[e] += __shfl_xor(lgt[e], off);
  }
  if (l == 0) {
    float scn = rsqrtf(ss * (1.f/1024.f) + EPSF);
    float lmax = fmaxf(fmaxf(lgt[0], lgt[1]), fmaxf(lgt[2], lgt[3]));
    float p[4];
#pragma unroll
    for (int e = 0; e < 4; ++e) p[e] = expf(scn * (lgt[e] - lmax));
    int i1 = 0;
    for (int e = 1; e < 4; ++e) if (p[e] > p[i1]) i1 = e;
    int i2 = (i1 == 0) ? 1 : 0;
    for (int e = 0; e < 4; ++e) if (e != i1 && p[e] > p[i2]) i2 = e;
    float wsum = p[i1] + p[i2];
    float4 ov = {0.f, 0.f, 0.f, 0.f};
    ((float*)&ov)[i1] = p[i1] / wsum;
    ((float*)&ov)[i2] = p[i2] / wsum;
    *(float4*)&comb[(size_t)row * 4] = ov;
    rsel[row] = i1 * 4 + i2;
  }
}

// ---- per-expert compaction: slot0 (top-1) list then slot1 (top-2) list -----
__global__ __launch_bounds__(1024) void compact_k(
    const int* __restrict__ rsel, int* __restrict__ idxb, int* __restrict__ meta) {
  int e = blockIdx.x;
  int t = threadIdx.x;
  int lane = t & 63, wid = t >> 6;
  int base = t * 4;
  int r[4];
#pragma unroll
  for (int j = 0; j < 4; ++j) r[j] = rsel[base + j];
  __shared__ int wsum[16], woff[16], totA;
  int outb = e * 4096;
#pragma unroll
  for (int pass = 0; pass < 2; ++pass) {
    int loc[4], c = 0;
#pragma unroll
    for (int j = 0; j < 4; ++j) {
      int sel = pass ? (r[j] & 3) : (r[j] >> 2);
      loc[j] = (sel == e) ? 1 : 0;
      c += loc[j];
    }
    int v = c;
#pragma unroll
    for (int off = 1; off < 64; off <<= 1) {
      int o = __shfl_up(v, off);
      if (lane >= off) v += o;
    }
    if (lane == 63) wsum[wid] = v;
    __syncthreads();
    if (t < 16) {
      int s = wsum[t];
      int vv = s;
#pragma unroll
      for (int off = 1; off < 16; off <<= 1) {
        int o = __shfl_up(vv, off);
        if (t >= off) vv += o;
      }
      woff[t] = vv - s;
      if (t == 15) {
        if (pass == 0) { totA = vv; meta[e * 4 + 0] = vv; }
        else           { meta[e * 4 + 1] = totA + vv; }
      }
    }
    __syncthreads();
    int pbase = (pass ? totA : 0) + woff[wid] + (v - c);
#pragma unroll
    for (int j = 0; j < 4; ++j)
      if (loc[j]) idxb[outb + pbase++] = base + j;
    __syncthreads();
  }
}

__global__ void eoff_k(int* __restrict__ meta) {
  if (threadIdx.x == 0 && blockIdx.x == 0) {
    int run = 0;
    for (int e = 0; e < 4; ++e) { meta[e * 4 + 2] = run; run += meta[e * 4 + 1]; }
  }
}

// ---------------- launch ----------------------------------------------------
extern "C" void kernel_launch(void* const* d_in, const int* in_sizes, int n_in,
                              void* d_out, int out_size, void* d_ws, size_t ws_size,
                              hipStream_t stream) {
  const float* x    = (const float*)d_in[0];
  const float* g1   = (const float*)d_in[1];
  const float* g2   = (const float*)d_in[2];
  const float* wq   = (const float*)d_in[3];
  const float* wk   = (const float*)d_in[4];
  const float* wv   = (const float*)d_in[5];
  const float* wo   = (const float*)d_in[6];
  const float* gate = (const float*)d_in[7];
  const float* w1   = (const float*)d_in[8];
  const float* w2   = (const float*)d_in[9];
  const float* w3   = (const float*)d_in[10];
  float* out = (float*)d_out;

  char* p = (char*)d_ws;
  size_t off = 0;
  auto carve = [&](size_t bytes) {
    void* r = p + off;
    off = (off + bytes + 255) & ~(size_t)255;
    return r;
  };
  short* wqkvT = (short*)carve((size_t)1536 * 1024 * 2);
  short* woC3  = (short*)carve((size_t)1024 * 3072 * 2);
  short* w13T  = (short*)carve((size_t)NEXP * 6144 * 1024 * 2);
  short* w2T   = (short*)carve((size_t)NEXP * 1024 * 3072 * 2);
  short* xn1   = (short*)carve((size_t)NT * DIMD * 2);
  short* xn2   = (short*)carve((size_t)NT * DIMD * 2);
  float* qkv   = (float*)carve((size_t)NT * 1536 * 4);
  float* cosT  = (float*)carve((size_t)SS * 32 * 4);
  float* sinT  = (float*)carve((size_t)SS * 32 * 4);
  short* Qb    = (short*)carve((size_t)BB * NH * SS * HD * 2);
  short* Kb    = (short*)carve((size_t)BB * NKV * SS * HD * 2);
  short* Vt    = (short*)carve((size_t)BB * NKV * HD * SS * 2);
  short* AO2   = (short*)carve((size_t)NT * 2048 * 2);
  float* comb  = (float*)carve((size_t)NT * 4 * 4);
  int*   rsel  = (int*)carve((size_t)NT * 4);
  int*   idxb  = (int*)carve((size_t)NEXP * 4096 * 4);
  int*   meta  = (int*)carve((size_t)16 * 4);
  short* Hb    = (short*)carve((size_t)(2 * NT + 256) * 3072 * 2);
  (void)ws_size; (void)in_sizes; (void)n_in; (void)out_size;

  dim3 blk(256);
  // weight prep
  transpose_k<0><<<dim3(16, 16), blk, 0, stream>>>(wq, wqkvT, (short*)0, 1024, 1024, 0, 0, 1024, 0, 0);
  transpose_k<0><<<dim3(4, 16), blk, 0, stream>>>(wk, wqkvT + (size_t)1024 * 1024, (short*)0, 1024, 256, 0, 0, 1024, 0, 0);
  transpose_k<0><<<dim3(4, 16), blk, 0, stream>>>(wv, wqkvT + (size_t)1280 * 1024, (short*)0, 1024, 256, 0, 0, 1024, 0, 0);
  // woC3 [1024][3072] = [Whi | Wlo | Whi]
  transpose_k<1><<<dim3(16, 16), blk, 0, stream>>>(wo, woC3, woC3 + 1024, 1024, 1024, 0, 0, 3072, 3072, 0);
  transpose_k<0><<<dim3(16, 16), blk, 0, stream>>>(wo, woC3 + 2048, (short*)0, 1024, 1024, 0, 0, 3072, 0, 0);
  // w1/w3 interleaved at 16-col granularity into w13T [E][6144][1024]
  transpose_k<0><<<dim3(48, 16, 4), blk, 0, stream>>>(w1, w13T, (short*)0, 1024, 3072, (size_t)1024*3072, (size_t)6144*1024, 1024, 0, 1);
  transpose_k<0><<<dim3(48, 16, 4), blk, 0, stream>>>(w3, w13T, (short*)0, 1024, 3072, (size_t)1024*3072, (size_t)6144*1024, 1024, 0, 2);
  transpose_k<0><<<dim3(16, 48, 4), blk, 0, stream>>>(w2, w2T, (short*)0, 3072, 1024, (size_t)3072*1024, (size_t)1024*3072, 3072, 0, 0);
  rope_tables_k<<<dim3(256), blk, 0, stream>>>(cosT, sinT);

  // attention
  rmsnorm_k<<<dim3(NT), blk, 0, stream>>>(x, g1, xn1);
  gemm_bt<0,0><<<dim3(32, 12), blk, 0, stream>>>(xn1, wqkvT, qkv, (short*)0, (const float*)0,
      (const int*)0, (const int*)0, (const float*)0, NT, 1536, 1024, 1024, 1024);
  rope_scatter_k<<<dim3(NT), blk, 0, stream>>>(qkv, cosT, sinT, Qb, Kb, Vt);
  attn_k<<<dim3(512), dim3(512), 0, stream>>>(Qb, Kb, Vt, AO2);
  // O-projection split precision in ONE GEMM: K=3072, A=[hi|hi|lo] via fold,
  // B=[Whi|Wlo|Whi]; +x residual.
  gemm_bt<1,1><<<dim3(32, 8), blk, 0, stream>>>(AO2, woC3, out, (short*)0, x,
      (const int*)0, (const int*)0, (const float*)0, NT, 1024, 3072, 2048, 3072);

  // MoE
  rmsnorm_k<<<dim3(NT), blk, 0, stream>>>(out, g2, xn2);
  routing_k<<<dim3(NT), dim3(64), 0, stream>>>(out, g2, gate, comb, rsel);
  compact_k<<<dim3(4), dim3(1024), 0, stream>>>(rsel, idxb, meta);
  eoff_k<<<dim3(1), dim3(64), 0, stream>>>(meta);
  // all experts in one dispatch: 128^2 gather-GEMM + fused SwiGLU -> Hb
  gemm_bt<7,0><<<dim3(32, 48, 4), blk, 0, stream>>>(xn2, w13T, (float*)0, Hb, (const float*)0,
      idxb, meta, (const float*)0, NT, 6144, 1024, 1024, 1024);
  // w2 scatter-accumulate, both slots in one dispatch (atomicAdd f32)
  gemm_bt<6,0><<<dim3(32, 8, 8), blk, 0, stream>>>(Hb, w2T, out, (short*)0, (const float*)0,
      idxb, meta, comb, NT, 1024, 3072, 3072, 3072);
}

// Round 9
// 476.412 us; speedup vs baseline: 1.3309x; 1.0034x over previous
//
#include <hip/hip_runtime.h>
#include <stdint.h>

#define DIMD 1024
#define NH 16
#define NKV 4
#define HD 64
#define NEXP 4
#define HID 3072
#define BB 2
#define SS 2048
#define NT (BB*SS)
#define EPSF 1.1920928955078125e-07f
#define LOG2E 1.4426950408889634f

typedef short short8 __attribute__((ext_vector_type(8)));
typedef short short4v __attribute__((ext_vector_type(4)));
typedef float f32x4 __attribute__((ext_vector_type(4)));

__device__ __forceinline__ short f2bf(float f) {
  union { float f; unsigned u; } c; c.f = f;
  unsigned u = c.u;
  unsigned r = u + 0x7fffu + ((u >> 16) & 1u);
  return (short)(r >> 16);
}
__device__ __forceinline__ float bf2f(short s) {
  union { unsigned u; float f; } c;
  c.u = ((unsigned)(unsigned short)s) << 16;
  return c.f;
}
__device__ __forceinline__ float fexp2(float x) {
#if __has_builtin(__builtin_amdgcn_exp2f)
  return __builtin_amdgcn_exp2f(x);
#else
  return exp2f(x);
#endif
}

__device__ __forceinline__ f32x4 mfma16(short8 a, short8 b, f32x4 c) {
  return __builtin_amdgcn_mfma_f32_16x16x32_bf16(a, b, c, 0, 0, 0);
}

#define GLOAD16(gp, lp) __builtin_amdgcn_global_load_lds( \
    (const __attribute__((address_space(1))) void*)(gp),  \
    (__attribute__((address_space(3))) void*)(lp), 16, 0, 0)

// ---------------- transpose + f32->bf16 convert ------------------------------
template<int SPLIT>
__global__ __launch_bounds__(256) void transpose_k(
    const float* __restrict__ in, short* __restrict__ o1, short* __restrict__ o2,
    int Krows, int N, size_t inStride, size_t outStride, int ldo1, int ldo2,
    int mapMode) {
  __shared__ float tile[64][68];
  const float* inp = in + (size_t)blockIdx.z * inStride;
  short* hp = o1 + (size_t)blockIdx.z * outStride;
  short* lp = SPLIT ? (o2 + (size_t)blockIdx.z * outStride) : (short*)0;
  int tx = threadIdx.x & 15, ty = threadIdx.x >> 4;  // 16 x 16
  int n0 = blockIdx.x * 64, k0 = blockIdx.y * 64;
#pragma unroll
  for (int p = 0; p < 4; ++p) {
    int k = p * 16 + ty;
    float4 v = *(const float4*)&inp[(size_t)(k0 + k) * N + n0 + tx * 4];
    *(float4*)&tile[k][tx * 4] = v;
  }
  __syncthreads();
#pragma unroll
  for (int p = 0; p < 4; ++p) {
    int n = n0 + p * 16 + ty;
    int np = mapMode ? ((n >> 4) * 32 + (n & 15) + ((mapMode == 2) ? 16 : 0)) : n;
    int k4 = tx * 4;
    short4v hv, lv;
#pragma unroll
    for (int j = 0; j < 4; ++j) {
      float v = tile[k4 + j][p * 16 + ty];
      short h_ = f2bf(v);
      hv[j] = h_;
      if (SPLIT) lv[j] = f2bf(v - bf2f(h_));
    }
    *(short4v*)&hp[(size_t)np * ldo1 + k0 + k4] = hv;
    if (SPLIT) *(short4v*)&lp[(size_t)np * ldo2 + k0 + k4] = lv;
  }
}

// ---------------- RMSNorm (f32 in -> bf16 out) ------------------------------
__global__ __launch_bounds__(256) void rmsnorm_k(
    const float* __restrict__ x, const float* __restrict__ g, short* __restrict__ outq) {
  int row = blockIdx.x;
  int t = threadIdx.x;
  const float4* xr = (const float4*)(x + (size_t)row * DIMD);
  float4 v = xr[t];
  float ss = v.x*v.x + v.y*v.y + v.z*v.z + v.w*v.w;
#pragma unroll
  for (int off = 1; off < 64; off <<= 1) ss += __shfl_xor(ss, off);
  __shared__ float red[4];
  if ((t & 63) == 0) red[t >> 6] = ss;
  __syncthreads();
  float tot = red[0] + red[1] + red[2] + red[3];
  float scn = rsqrtf(tot * (1.f/1024.f) + EPSF);
  float4 gv = ((const float4*)g)[t];
  short4v ov;
  ov[0] = f2bf(v.x * scn * gv.x);
  ov[1] = f2bf(v.y * scn * gv.y);
  ov[2] = f2bf(v.z * scn * gv.z);
  ov[3] = f2bf(v.w * scn * gv.w);
  ((short4v*)outq)[(size_t)row * 256 + t] = ov;
}

// ---------------- RoPE tables ----------------------------------------------
__global__ __launch_bounds__(256) void rope_tables_k(
    float* __restrict__ cosT, float* __restrict__ sinT) {
  int t = blockIdx.x * 256 + threadIdx.x;  // 2048*32
  int s = t >> 5, i = t & 31;
  float invf = powf(10000.0f, -(float)i / 32.0f);
  float a = (float)s * invf;
  cosT[t] = cosf(a);
  sinT[t] = sinf(a);
}

// ---------------- RoPE apply + scatter to attention layouts -----------------
#define QSCALE 0.18033688011112042f
__global__ __launch_bounds__(256) void rope_scatter_k(
    const float* __restrict__ qkv, const float* __restrict__ cosT,
    const float* __restrict__ sinT, short* __restrict__ Qb,
    short* __restrict__ Kb, short* __restrict__ Vt) {
  int r = blockIdx.x;
  int t = threadIdx.x;
  int b = r >> 11, s = r & 2047;
  __shared__ float row[1536];
  const float* rp = qkv + (size_t)r * 1536;
  for (int i = t; i < 1536; i += 256) row[i] = rp[i];
  __syncthreads();
  const float* cs = cosT + s * 32;
  const float* sn = sinT + s * 32;
  {
    int c = t * 4, hh = c >> 6, j = c & 63;
    short4v ov;
#pragma unroll
    for (int u = 0; u < 4; ++u) {
      int jj = j + u;
      float xv = row[hh*64 + jj];
      float rot = (jj < 32) ? -row[hh*64 + jj + 32] : row[hh*64 + jj - 32];
      ov[u] = f2bf((xv * cs[jj & 31] + rot * sn[jj & 31]) * QSCALE);
    }
    *(short4v*)&Qb[((size_t)(b*NH + hh) * SS + s) * 64 + j] = ov;
  }
  if (t < 64) {
    int c = t * 4, kvh = c >> 6, j = c & 63;
    short4v ov;
#pragma unroll
    for (int u = 0; u < 4; ++u) {
      int jj = j + u;
      float xv = row[1024 + kvh*64 + jj];
      float rot = (jj < 32) ? -row[1024 + kvh*64 + jj + 32] : row[1024 + kvh*64 + jj - 32];
      ov[u] = f2bf(xv * cs[jj & 31] + rot * sn[jj & 31]);
    }
    *(short4v*)&Kb[((size_t)(b*NKV + kvh) * SS + s) * 64 + j] = ov;
  } else if (t < 128) {
    int c = (t - 64) * 4, kvh = c >> 6, j = c & 63;
#pragma unroll
    for (int u = 0; u < 4; ++u)
      Vt[((size_t)(b*NKV + kvh) * 64 + j + u) * SS + s] = f2bf(row[1280 + kvh*64 + j + u]);
  }
}

// ---------------- 128x128 GEMM (single-buffered, proven) --------------------
// EPI: 0 C=v | 1 C=v+R | 6 batched w2: compact rows, atomic scatter |
//      7 batched w13: gather-A by token list, fused SwiGLU -> Cb bf16.
// AFOLD: A k-index folds (k<1024?k:k-1024) for split-precision O-proj.
template<int EPI, int AFOLD>
__global__ __launch_bounds__(256, 2) void gemm_bt(
    const short* __restrict__ A, const short* __restrict__ Bt,
    float* __restrict__ C, short* __restrict__ Cb,
    const float* __restrict__ R,
    const int* __restrict__ idx, const int* __restrict__ meta,
    const float* __restrict__ comb,
    int M, int N, int K, int lda, int ldb) {
  __shared__ short As[128*64];
  __shared__ short Bs[128*64];
  int nx = gridDim.x, ny = gridDim.y;
  int nwg = nx * ny * gridDim.z;
  int o = blockIdx.x + nx * (blockIdx.y + ny * blockIdx.z);
  int xcd = o & 7, loc = o >> 3;
  int q = nwg >> 3, rr = nwg & 7;
  int wg = (xcd < rr ? xcd * (q + 1) : rr * (q + 1) + (xcd - rr) * q) + loc;
  int bm = wg % nx; int t1 = wg / nx; int bn = t1 % ny; int bz = t1 / ny;
  int tid = threadIdx.x;
  int w = tid >> 6, lane = tid & 63;
  int m0 = bm * 128, n0 = bn * 128;
  int cnt = M, abase = 0, eidx = 0, hrow0 = 0;
  const int* list = idx;
  if (EPI == 7) {
    const int* mp = meta + bz * 4;
    cnt = mp[1]; hrow0 = mp[2];
    list = idx + bz * 4096;
    Bt += (size_t)bz * 6144 * ldb;
    if (m0 >= cnt) return;
  }
  if (EPI == 6) {
    eidx = bz >> 1; int slot = bz & 1;
    const int* mp = meta + eidx * 4;
    int cA = mp[0], cT = mp[1];
    cnt = slot ? (cT - cA) : cA;
    abase = mp[2] + (slot ? cA : 0);
    list = idx + eidx * 4096 + (slot ? cA : 0);
    Bt += (size_t)eidx * 1024 * ldb;
    if (m0 >= cnt) return;
  }
  int wr = (w >> 1) * 64, wc = (w & 1) * 64;
  int l15 = lane & 15, lg = lane >> 4;
  int srow = lane >> 3, sslot = lane & 7;
  const short* aptr[4];
  const short* bptr[4];
#pragma unroll
  for (int i = 0; i < 4; ++i) {
    int row = i * 32 + w * 8 + srow;
    int gs = (sslot ^ (row & 7)) * 8;
    int am = m0 + row;
    if (EPI == 7) am = list[am < cnt ? am : cnt - 1];
    else if (EPI == 6) am = abase + am;
    aptr[i] = A + (size_t)am * lda + gs;
    bptr[i] = Bt + (size_t)(n0 + row) * ldb + gs;
  }
  f32x4 acc[4][4] = {};
  int nK = K >> 6;
  for (int kt = 0; kt < nK; ++kt) {
    int k0 = kt << 6;
    int ak0 = AFOLD ? (kt < 16 ? k0 : k0 - 1024) : k0;
    __syncthreads();
#pragma unroll
    for (int i = 0; i < 4; ++i) {
      int r0 = i * 32 + w * 8;
      GLOAD16(aptr[i] + ak0, &As[r0 * 64]);
      GLOAD16(bptr[i] + k0, &Bs[r0 * 64]);
    }
    asm volatile("s_waitcnt vmcnt(0)" ::: "memory");
    __syncthreads();
#pragma unroll
    for (int kh = 0; kh < 2; ++kh) {
      short8 af[4], bfv[4];
#pragma unroll
      for (int mi = 0; mi < 4; ++mi) {
        int row = wr + mi * 16 + l15;
        int sl = (lg + kh * 4) ^ (row & 7);
        af[mi] = *(const short8*)&As[row * 64 + sl * 8];
        int rowb = wc + mi * 16 + l15;
        int slb = (lg + kh * 4) ^ (rowb & 7);
        bfv[mi] = *(const short8*)&Bs[rowb * 64 + slb * 8];
      }
#pragma unroll
      for (int mi = 0; mi < 4; ++mi)
#pragma unroll
        for (int ni = 0; ni < 4; ++ni)
          acc[mi][ni] = mfma16(af[mi], bfv[ni], acc[mi][ni]);
    }
  }
#pragma unroll
  for (int mi = 0; mi < 4; ++mi) {
#pragma unroll
    for (int i = 0; i < 4; ++i) {
      int m = m0 + wr + mi * 16 + 4 * lg + i;
      if (EPI == 7) {
        if (m < cnt) {
          int g0 = (n0 + wc) >> 5;
#pragma unroll
          for (int p = 0; p < 2; ++p) {
            float xg = acc[mi][2*p][i];
            float yg = acc[mi][2*p+1][i];
            float sg = 1.f / (1.f + fexp2(-xg * LOG2E));
            Cb[(size_t)(hrow0 + m) * 3072 + (g0 + p) * 16 + l15] = f2bf(xg * sg * yg);
          }
        }
      } else if (EPI == 6) {
        if (m < cnt) {
          int tok = list[m];
          float wgt = comb[tok * 4 + eidx];
#pragma unroll
          for (int ni = 0; ni < 4; ++ni) {
            int n = n0 + wc + ni * 16 + l15;
            atomicAdd(&C[(size_t)tok * 1024 + n], wgt * acc[mi][ni][i]);
          }
        }
      } else {
#pragma unroll
        for (int ni = 0; ni < 4; ++ni) {
          int n = n0 + wc + ni * 16 + l15;
          size_t cidx = (size_t)m * N + n;
          float v = acc[mi][ni][i];
          if (EPI == 0)      C[cidx] = v;
          else               C[cidx] = v + R[cidx];
        }
      }
    }
  }
}

// ---------------- Flash attention: 8 waves, two q-tiles, LDS K/V ------------
// K/V staged once per block; DOUBLE-BUFFERED with counted-wait 2-phase:
// next tile's global_load_lds issue BEFORE compute, waits AFTER compute
// (raw s_barrier; stage latency hides under QK/exp/PV).
__global__ __launch_bounds__(512) void attn_k(
    const short* __restrict__ Qb, const short* __restrict__ Kb,
    const short* __restrict__ Vt, short* __restrict__ AO2) {
  int id = blockIdx.x;
  int qp = ((id & 15) + ((id >> 8) << 3)) & 15;
  int hb = (id >> 4) & 31;
  int h = hb & 15, b = hb >> 4;
  int tid = threadIdx.x;
  int w = tid >> 6, lane = tid & 63;
  int half = w >> 2, w4 = w & 3;
  int l15 = lane & 15, lg = lane >> 4;
  int kvh = h >> 2;
  __shared__ short Ks[2][64 * 64];
  __shared__ short Vs[2][64 * 64];
  __shared__ short P[8][16 * 72];
  short* Pw = P[w];
  const short* Qp = Qb + (size_t)(b * NH + h) * SS * 64;
  const short* Kp = Kb + (size_t)(b * NKV + kvh) * SS * 64;
  const short* Vp = Vt + (size_t)(b * NKV + kvh) * 64 * SS;
  int qt = half ? (31 - qp) : qp;
  int kmax = 31 - qp;                      // = max(qp, 31-qp) since qp<16
  int qbase = qt * 64 + w4 * 16;
  int qrow0 = qbase + 4 * lg;
  short8 aq0 = *(const short8*)&Qp[(size_t)(qbase + l15) * 64 + 8 * lg];
  short8 aq1 = *(const short8*)&Qp[(size_t)(qbase + l15) * 64 + 8 * lg + 32];
  int srow = lane >> 3, sslot = lane & 7;
  int strow = w * 8 + srow;                // 0..63
  int sgs = (sslot ^ (strow & 7)) * 8;
  const short* ksrc = Kp + (size_t)strow * 64 + sgs;   // += k0*64 per tile
  const short* vsrc = Vp + (size_t)strow * SS + sgs;   // += k0 per tile
  f32x4 o4[4] = {};
  float lst[4] = {0.f, 0.f, 0.f, 0.f};
  // prologue: stage tile 0 into buffer 0
  GLOAD16(ksrc, &Ks[0][(w * 8) * 64]);
  GLOAD16(vsrc, &Vs[0][(w * 8) * 64]);
  asm volatile("s_waitcnt vmcnt(0)" ::: "memory");
  __builtin_amdgcn_s_barrier();
  for (int kt = 0; kt <= kmax; ++kt) {
    int cur = kt & 1;
    if (kt < kmax) {  // issue next tile BEFORE compute (hides under compute)
      int k1 = (kt + 1) * 64;
      GLOAD16(ksrc + (size_t)k1 * 64, &Ks[cur ^ 1][(w * 8) * 64]);
      GLOAD16(vsrc + k1, &Vs[cur ^ 1][(w * 8) * 64]);
    }
    if (kt <= qt) {
      int k0 = kt * 64;
      const short* Kc = &Ks[cur][0];
      const short* Vc = &Vs[cur][0];
      f32x4 sc[4] = {};
      short8 bk[2][4];
#pragma unroll
      for (int kh = 0; kh < 2; ++kh)
#pragma unroll
        for (int ni = 0; ni < 4; ++ni) {
          int row = ni * 16 + l15;
          int sl = (lg + kh * 4) ^ (row & 7);
          bk[kh][ni] = *(const short8*)&Kc[row * 64 + sl * 8];
        }
      __builtin_amdgcn_s_setprio(1);
#pragma unroll
      for (int kh = 0; kh < 2; ++kh)
#pragma unroll
        for (int ni = 0; ni < 4; ++ni)
          sc[ni] = mfma16(kh ? aq1 : aq0, bk[kh][ni], sc[ni]);
      __builtin_amdgcn_s_setprio(0);
      short8 bv[2][4];
#pragma unroll
      for (int kh = 0; kh < 2; ++kh)
#pragma unroll
        for (int di = 0; di < 4; ++di) {
          int row = di * 16 + l15;
          int sl = (lg + kh * 4) ^ (row & 7);
          bv[kh][di] = *(const short8*)&Vc[row * 64 + sl * 8];
        }
      if (kt == qt) {
#pragma unroll
        for (int ni = 0; ni < 4; ++ni)
#pragma unroll
          for (int i = 0; i < 4; ++i)
            if (k0 + ni*16 + l15 > qrow0 + i) sc[ni][i] = -3.0e38f;
      }
#pragma unroll
      for (int i = 0; i < 4; ++i) {
        float ps = 0.f;
#pragma unroll
        for (int ni = 0; ni < 4; ++ni) {
          float pv = fexp2(sc[ni][i]);   // masked -> exp2(-3e38) = +0
          sc[ni][i] = pv;
          ps += pv;
        }
        lst[i] += ps;
      }
#pragma unroll
      for (int ni = 0; ni < 4; ++ni)
#pragma unroll
        for (int i = 0; i < 4; ++i)
          Pw[(4*lg + i) * 72 + ni*16 + l15] = f2bf(sc[ni][i]);
      __builtin_amdgcn_s_setprio(1);
#pragma unroll
      for (int kh = 0; kh < 2; ++kh) {
        short8 ap = *(const short8*)&Pw[l15 * 72 + 8*lg + 32*kh];
#pragma unroll
        for (int di = 0; di < 4; ++di)
          o4[di] = mfma16(ap, bv[kh][di], o4[di]);
      }
      __builtin_amdgcn_s_setprio(0);
    }
    // next-tile loads landed during compute; my LDS reads retired
    asm volatile("s_waitcnt vmcnt(0) lgkmcnt(0)" ::: "memory");
    __builtin_amdgcn_s_barrier();
  }
  float rinv[4];
#pragma unroll
  for (int i = 0; i < 4; ++i) {
    float s = lst[i];
    s += __shfl_xor(s, 1); s += __shfl_xor(s, 2);
    s += __shfl_xor(s, 4); s += __shfl_xor(s, 8);
    rinv[i] = 1.f / s;
  }
#pragma unroll
  for (int di = 0; di < 4; ++di) {
#pragma unroll
    for (int i = 0; i < 4; ++i) {
      float val = o4[di][i] * rinv[i];
      short hi_ = f2bf(val);
      short lo_ = f2bf(val - bf2f(hi_));
      size_t idx = ((size_t)(b * SS + qrow0 + i)) * 2048 + h*64 + di*16 + l15;
      AO2[idx] = hi_;
      AO2[idx + 1024] = lo_;
    }
  }
}

// ------- MoE routing + fused RMSNorm (reads x1 once; writes xn2 + comb) -----
// Expert RANKING depends only on lgt ordering (scn>0 monotone) -> identical
// selection to the unfused version; xn2 math identical to rmsnorm_k.
__global__ __launch_bounds__(64) void routing_k(
    const float* __restrict__ x1, const float* __restrict__ g2,
    const float* __restrict__ gate, float* __restrict__ comb,
    int* __restrict__ rsel, short* __restrict__ xn2) {
  int row = blockIdx.x;
  int l = threadIdx.x;
  const float* xr = x1 + (size_t)row * 1024;
  float ss = 0.f;
  float lgt[4] = {0.f, 0.f, 0.f, 0.f};
  for (int it = 0; it < 4; ++it) {
    int d0 = it * 256 + l * 4;
    float4 v = *(const float4*)&xr[d0];
    float4 gv = *(const float4*)&g2[d0];
    const float* vp = (const float*)&v;
    const float* gp = (const float*)&gv;
#pragma unroll
    for (int u = 0; u < 4; ++u) {
      float xv = vp[u];
      ss += xv * xv;
      float xg = xv * gp[u];
      float4 gr = *(const float4*)&gate[(size_t)(d0 + u) * 4];
      lgt[0] += xg * gr.x; lgt[1] += xg * gr.y;
      lgt[2] += xg * gr.z; lgt[3] += xg * gr.w;
    }
  }
#pragma unroll
  for (int off = 1; off < 64; off <<= 1) {
    ss += __shfl_xor(ss, off);
#pragma unroll
    for (int e = 0; e < 4; ++e) lgt[e] += __shfl_xor(lgt[e], off);
  }
  float scn = rsqrtf(ss * (1.f/1024.f) + EPSF);
  // fused RMSNorm output (same formula as rmsnorm_k)
  for (int it = 0; it < 4; ++it) {
    int d0 = it * 256 + l * 4;
    float4 v = *(const float4*)&xr[d0];
    float4 gv = *(const float4*)&g2[d0];
    short4v ov;
    ov[0] = f2bf(v.x * scn * gv.x);
    ov[1] = f2bf(v.y * scn * gv.y);
    ov[2] = f2bf(v.z * scn * gv.z);
    ov[3] = f2bf(v.w * scn * gv.w);
    *(short4v*)&xn2[(size_t)row * 1024 + d0] = ov;
  }
  if (l == 0) {
    float lmax = fmaxf(fmaxf(lgt[0], lgt[1]), fmaxf(lgt[2], lgt[3]));
    float p[4];
#pragma unroll
    for (int e = 0; e < 4; ++e) p[e] = expf(scn * (lgt[e] - lmax));
    int i1 = 0;
    for (int e = 1; e < 4; ++e) if (p[e] > p[i1]) i1 = e;
    int i2 = (i1 == 0) ? 1 : 0;
    for (int e = 0; e < 4; ++e) if (e != i1 && p[e] > p[i2]) i2 = e;
    float wsum = p[i1] + p[i2];
    float4 ov = {0.f, 0.f, 0.f, 0.f};
    ((float*)&ov)[i1] = p[i1] / wsum;
    ((float*)&ov)[i2] = p[i2] / wsum;
    *(float4*)&comb[(size_t)row * 4] = ov;
    rsel[row] = i1 * 4 + i2;
  }
}

// ---- compaction, all experts in ONE block (fused expert-offset prefix) -----
__global__ __launch_bounds__(1024) void compact_k(
    const int* __restrict__ rsel, int* __restrict__ idxb, int* __restrict__ meta) {
  int t = threadIdx.x;
  int lane = t & 63, wid = t >> 6;
  int base = t * 4;
  int r[4];
#pragma unroll
  for (int j = 0; j < 4; ++j) r[j] = rsel[base + j];
  __shared__ int wsum[16], woff[16], shA, shT;
  int run = 0;
  for (int e = 0; e < 4; ++e) {
    int outb = e * 4096;
#pragma unroll
    for (int pass = 0; pass < 2; ++pass) {
      int loc[4], c = 0;
#pragma unroll
      for (int j = 0; j < 4; ++j) {
        int sel = pass ? (r[j] & 3) : (r[j] >> 2);
        loc[j] = (sel == e) ? 1 : 0;
        c += loc[j];
      }
      int v = c;
#pragma unroll
      for (int off = 1; off < 64; off <<= 1) {
        int o = __shfl_up(v, off);
        if (lane >= off) v += o;
      }
      if (lane == 63) wsum[wid] = v;
      __syncthreads();
      if (t < 16) {
        int s = wsum[t];
        int vv = s;
#pragma unroll
        for (int off = 1; off < 16; off <<= 1) {
          int o = __shfl_up(vv, off);
          if (t >= off) vv += o;
        }
        woff[t] = vv - s;
        if (t == 15) { if (pass == 0) shA = vv; else shT = shA + vv; }
      }
      __syncthreads();
      int pbase = (pass ? shA : 0) + woff[wid] + (v - c);
#pragma unroll
      for (int j = 0; j < 4; ++j)
        if (loc[j]) idxb[outb + pbase++] = base + j;
      __syncthreads();
    }
    if (t == 0) { meta[e*4+0] = shA; meta[e*4+1] = shT; meta[e*4+2] = run; }
    run += shT;
    __syncthreads();
  }
}

// ---------------- launch ----------------------------------------------------
extern "C" void kernel_launch(void* const* d_in, const int* in_sizes, int n_in,
                              void* d_out, int out_size, void* d_ws, size_t ws_size,
                              hipStream_t stream) {
  const float* x    = (const float*)d_in[0];
  const float* g1   = (const float*)d_in[1];
  const float* g2   = (const float*)d_in[2];
  const float* wq   = (const float*)d_in[3];
  const float* wk   = (const float*)d_in[4];
  const float* wv   = (const float*)d_in[5];
  const float* wo   = (const float*)d_in[6];
  const float* gate = (const float*)d_in[7];
  const float* w1   = (const float*)d_in[8];
  const float* w2   = (const float*)d_in[9];
  const float* w3   = (const float*)d_in[10];
  float* out = (float*)d_out;

  char* p = (char*)d_ws;
  size_t off = 0;
  auto carve = [&](size_t bytes) {
    void* r = p + off;
    off = (off + bytes + 255) & ~(size_t)255;
    return r;
  };
  short* wqkvT = (short*)carve((size_t)1536 * 1024 * 2);
  short* woC3  = (short*)carve((size_t)1024 * 3072 * 2);
  short* w13T  = (short*)carve((size_t)NEXP * 6144 * 1024 * 2);
  short* w2T   = (short*)carve((size_t)NEXP * 1024 * 3072 * 2);
  short* xn1   = (short*)carve((size_t)NT * DIMD * 2);
  short* xn2   = (short*)carve((size_t)NT * DIMD * 2);
  float* qkv   = (float*)carve((size_t)NT * 1536 * 4);
  float* cosT  = (float*)carve((size_t)SS * 32 * 4);
  float* sinT  = (float*)carve((size_t)SS * 32 * 4);
  short* Qb    = (short*)carve((size_t)BB * NH * SS * HD * 2);
  short* Kb    = (short*)carve((size_t)BB * NKV * SS * HD * 2);
  short* Vt    = (short*)carve((size_t)BB * NKV * HD * SS * 2);
  short* AO2   = (short*)carve((size_t)NT * 2048 * 2);
  float* comb  = (float*)carve((size_t)NT * 4 * 4);
  int*   rsel  = (int*)carve((size_t)NT * 4);
  int*   idxb  = (int*)carve((size_t)NEXP * 4096 * 4);
  int*   meta  = (int*)carve((size_t)16 * 4);
  short* Hb    = (short*)carve((size_t)(2 * NT + 256) * 3072 * 2);
  (void)ws_size; (void)in_sizes; (void)n_in; (void)out_size;

  dim3 blk(256);
  // weight prep
  transpose_k<0><<<dim3(16, 16), blk, 0, stream>>>(wq, wqkvT, (short*)0, 1024, 1024, 0, 0, 1024, 0, 0);
  transpose_k<0><<<dim3(4, 16), blk, 0, stream>>>(wk, wqkvT + (size_t)1024 * 1024, (short*)0, 1024, 256, 0, 0, 1024, 0, 0);
  transpose_k<0><<<dim3(4, 16), blk, 0, stream>>>(wv, wqkvT + (size_t)1280 * 1024, (short*)0, 1024, 256, 0, 0, 1024, 0, 0);
  // woC3 [1024][3072] = [Whi | Wlo | Whi]
  transpose_k<1><<<dim3(16, 16), blk, 0, stream>>>(wo, woC3, woC3 + 1024, 1024, 1024, 0, 0, 3072, 3072, 0);
  transpose_k<0><<<dim3(16, 16), blk, 0, stream>>>(wo, woC3 + 2048, (short*)0, 1024, 1024, 0, 0, 3072, 0, 0);
  // w1/w3 interleaved at 16-col granularity into w13T [E][6144][1024]
  transpose_k<0><<<dim3(48, 16, 4), blk, 0, stream>>>(w1, w13T, (short*)0, 1024, 3072, (size_t)1024*3072, (size_t)6144*1024, 1024, 0, 1);
  transpose_k<0><<<dim3(48, 16, 4), blk, 0, stream>>>(w3, w13T, (short*)0, 1024, 3072, (size_t)1024*3072, (size_t)6144*1024, 1024, 0, 2);
  transpose_k<0><<<dim3(16, 48, 4), blk, 0, stream>>>(w2, w2T, (short*)0, 3072, 1024, (size_t)3072*1024, (size_t)1024*3072, 3072, 0, 0);
  rope_tables_k<<<dim3(256), blk, 0, stream>>>(cosT, sinT);

  // attention
  rmsnorm_k<<<dim3(NT), blk, 0, stream>>>(x, g1, xn1);
  gemm_bt<0,0><<<dim3(32, 12), blk, 0, stream>>>(xn1, wqkvT, qkv, (short*)0, (const float*)0,
      (const int*)0, (const int*)0, (const float*)0, NT, 1536, 1024, 1024, 1024);
  rope_scatter_k<<<dim3(NT), blk, 0, stream>>>(qkv, cosT, sinT, Qb, Kb, Vt);
  attn_k<<<dim3(512), dim3(512), 0, stream>>>(Qb, Kb, Vt, AO2);
  // O-projection split precision in ONE GEMM: K=3072, A=[hi|hi|lo] via fold,
  // B=[Whi|Wlo|Whi]; +x residual.
  gemm_bt<1,1><<<dim3(32, 8), blk, 0, stream>>>(AO2, woC3, out, (short*)0, x,
      (const int*)0, (const int*)0, (const float*)0, NT, 1024, 3072, 2048, 3072);

  // MoE (routing kernel also writes xn2 = RMSNorm(out)*g2)
  routing_k<<<dim3(NT), dim3(64), 0, stream>>>(out, g2, gate, comb, rsel, xn2);
  compact_k<<<dim3(1), dim3(1024), 0, stream>>>(rsel, idxb, meta);
  // all experts in one dispatch: 128^2 gather-GEMM + fused SwiGLU -> Hb
  gemm_bt<7,0><<<dim3(32, 48, 4), blk, 0, stream>>>(xn2, w13T, (float*)0, Hb, (const float*)0,
      idxb, meta, (const float*)0, NT, 6144, 1024, 1024, 1024);
  // w2 scatter-accumulate, both slots in one dispatch (atomicAdd f32)
  gemm_bt<6,0><<<dim3(32, 8, 8), blk, 0, stream>>>(Hb, w2T, out, (short*)0, (const float*)0,
      idxb, meta, comb, NT, 1024, 3072, 3072, 3072);
}

// Round 10
// 445.878 us; speedup vs baseline: 1.4221x; 1.0685x over previous
//
#include <hip/hip_runtime.h>
#include <stdint.h>

#define DIMD 1024
#define NH 16
#define NKV 4
#define HD 64
#define NEXP 4
#define HID 3072
#define BB 2
#define SS 2048
#define NT (BB*SS)
#define EPSF 1.1920928955078125e-07f
#define LOG2E 1.4426950408889634f

typedef short short8 __attribute__((ext_vector_type(8)));
typedef short short4v __attribute__((ext_vector_type(4)));
typedef float f32x4 __attribute__((ext_vector_type(4)));

__device__ __forceinline__ short f2bf(float f) {
  union { float f; unsigned u; } c; c.f = f;
  unsigned u = c.u;
  unsigned r = u + 0x7fffu + ((u >> 16) & 1u);
  return (short)(r >> 16);
}
__device__ __forceinline__ float bf2f(short s) {
  union { unsigned u; float f; } c;
  c.u = ((unsigned)(unsigned short)s) << 16;
  return c.f;
}
__device__ __forceinline__ float fexp2(float x) {
#if __has_builtin(__builtin_amdgcn_exp2f)
  return __builtin_amdgcn_exp2f(x);
#else
  return exp2f(x);
#endif
}

__device__ __forceinline__ f32x4 mfma16(short8 a, short8 b, f32x4 c) {
  return __builtin_amdgcn_mfma_f32_16x16x32_bf16(a, b, c, 0, 0, 0);
}

#define GLOAD16(gp, lp) __builtin_amdgcn_global_load_lds( \
    (const __attribute__((address_space(1))) void*)(gp),  \
    (__attribute__((address_space(3))) void*)(lp), 16, 0, 0)

// ======== unified prep: ALL weight transposes + rope tables + rmsnorm1 ======
// One dispatch; block ranges select the job (block-uniform branches).
//  [0,256)      wq -> wqkvT[0]        (16x16 tiles of 64)
//  [256,320)    wk -> wqkvT[1024k]    (4x16)
//  [320,384)    wv -> wqkvT[1280k]    (4x16)
//  [384,640)    wo -> woC3 hi|lo split (16x16)
//  [640,896)    wo -> woC3+2048 hi    (16x16)
//  [896,3968)   w1 -> w13T (map 1)    (48x16x4)
//  [3968,7040)  w3 -> w13T (map 2)    (48x16x4)
//  [7040,10112) w2 -> w2T             (16x48x4)
//  [10112,10368) rope cos/sin tables
//  [10368,14464) rmsnorm1: xn1 = bf16(RMSNorm(x)*g1)
__global__ __launch_bounds__(256) void prep_k(
    const float* __restrict__ wq, const float* __restrict__ wk,
    const float* __restrict__ wv, const float* __restrict__ wo,
    const float* __restrict__ w1, const float* __restrict__ w3,
    const float* __restrict__ w2,
    const float* __restrict__ x, const float* __restrict__ g1,
    short* __restrict__ wqkvT, short* __restrict__ woC3,
    short* __restrict__ w13T, short* __restrict__ w2T,
    float* __restrict__ cosT, float* __restrict__ sinT,
    short* __restrict__ xn1) {
  __shared__ float tile[64][68];
  int id = blockIdx.x;
  int t = threadIdx.x;
  if (id < 10112) {
    const float* in; short* o1; short* o2 = (short*)0;
    int split = 0, N, ldo1, ldo2 = 0, mm = 0, bx, by;
    if (id < 256)      { in = wq; o1 = wqkvT; N = 1024; ldo1 = 1024; bx = id % 16; by = id / 16; }
    else if (id < 320) { int r = id - 256; in = wk; o1 = wqkvT + (size_t)1024 * 1024; N = 256; ldo1 = 1024; bx = r % 4; by = r / 4; }
    else if (id < 384) { int r = id - 320; in = wv; o1 = wqkvT + (size_t)1280 * 1024; N = 256; ldo1 = 1024; bx = r % 4; by = r / 4; }
    else if (id < 640) { int r = id - 384; in = wo; o1 = woC3; o2 = woC3 + 1024; split = 1; N = 1024; ldo1 = 3072; ldo2 = 3072; bx = r % 16; by = r / 16; }
    else if (id < 896) { int r = id - 640; in = wo; o1 = woC3 + 2048; N = 1024; ldo1 = 3072; bx = r % 16; by = r / 16; }
    else if (id < 3968) { int r = id - 896; int bz = r / 768; int rr = r % 768;
      in = w1 + (size_t)bz * 1024 * 3072; o1 = w13T + (size_t)bz * 6144 * 1024;
      N = 3072; ldo1 = 1024; mm = 1; bx = rr % 48; by = rr / 48; }
    else if (id < 7040) { int r = id - 3968; int bz = r / 768; int rr = r % 768;
      in = w3 + (size_t)bz * 1024 * 3072; o1 = w13T + (size_t)bz * 6144 * 1024;
      N = 3072; ldo1 = 1024; mm = 2; bx = rr % 48; by = rr / 48; }
    else { int r = id - 7040; int bz = r / 768; int rr = r % 768;
      in = w2 + (size_t)bz * 3072 * 1024; o1 = w2T + (size_t)bz * 1024 * 3072;
      N = 1024; ldo1 = 3072; bx = rr % 16; by = rr / 16; }
    int tx = t & 15, ty = t >> 4;
    int n0 = bx * 64, k0 = by * 64;
#pragma unroll
    for (int p = 0; p < 4; ++p) {
      int k = p * 16 + ty;
      *(float4*)&tile[k][tx * 4] = *(const float4*)&in[(size_t)(k0 + k) * N + n0 + tx * 4];
    }
    __syncthreads();
#pragma unroll
    for (int p = 0; p < 4; ++p) {
      int n = n0 + p * 16 + ty;
      int np = mm ? ((n >> 4) * 32 + (n & 15) + ((mm == 2) ? 16 : 0)) : n;
      int k4 = tx * 4;
      short4v hv, lv;
#pragma unroll
      for (int j = 0; j < 4; ++j) {
        float v = tile[k4 + j][p * 16 + ty];
        short h_ = f2bf(v);
        hv[j] = h_;
        if (split) lv[j] = f2bf(v - bf2f(h_));
      }
      *(short4v*)&o1[(size_t)np * ldo1 + k0 + k4] = hv;
      if (split) *(short4v*)&o2[(size_t)np * ldo2 + k0 + k4] = lv;
    }
  } else if (id < 10368) {
    int tt = (id - 10112) * 256 + t;      // 2048*32 entries
    int s = tt >> 5, i = tt & 31;
    float invf = powf(10000.0f, -(float)i / 32.0f);
    float a = (float)s * invf;
    cosT[tt] = cosf(a);
    sinT[tt] = sinf(a);
  } else {
    int row = id - 10368;
    const float4* xr = (const float4*)(x + (size_t)row * DIMD);
    float4 v = xr[t];
    float ss = v.x*v.x + v.y*v.y + v.z*v.z + v.w*v.w;
#pragma unroll
    for (int off = 1; off < 64; off <<= 1) ss += __shfl_xor(ss, off);
    float* red = (float*)tile;
    if ((t & 63) == 0) red[t >> 6] = ss;
    __syncthreads();
    float tot = red[0] + red[1] + red[2] + red[3];
    float scn = rsqrtf(tot * (1.f/1024.f) + EPSF);
    float4 gv = ((const float4*)g1)[t];
    short4v ov;
    ov[0] = f2bf(v.x * scn * gv.x);
    ov[1] = f2bf(v.y * scn * gv.y);
    ov[2] = f2bf(v.z * scn * gv.z);
    ov[3] = f2bf(v.w * scn * gv.w);
    ((short4v*)xn1)[(size_t)row * 256 + t] = ov;
  }
}

// ---------------- RoPE apply + scatter to attention layouts -----------------
#define QSCALE 0.18033688011112042f
__global__ __launch_bounds__(256) void rope_scatter_k(
    const float* __restrict__ qkv, const float* __restrict__ cosT,
    const float* __restrict__ sinT, short* __restrict__ Qb,
    short* __restrict__ Kb, short* __restrict__ Vt) {
  int r = blockIdx.x;
  int t = threadIdx.x;
  int b = r >> 11, s = r & 2047;
  __shared__ float row[1536];
  const float* rp = qkv + (size_t)r * 1536;
  for (int i = t; i < 1536; i += 256) row[i] = rp[i];
  __syncthreads();
  const float* cs = cosT + s * 32;
  const float* sn = sinT + s * 32;
  {
    int c = t * 4, hh = c >> 6, j = c & 63;
    short4v ov;
#pragma unroll
    for (int u = 0; u < 4; ++u) {
      int jj = j + u;
      float xv = row[hh*64 + jj];
      float rot = (jj < 32) ? -row[hh*64 + jj + 32] : row[hh*64 + jj - 32];
      ov[u] = f2bf((xv * cs[jj & 31] + rot * sn[jj & 31]) * QSCALE);
    }
    *(short4v*)&Qb[((size_t)(b*NH + hh) * SS + s) * 64 + j] = ov;
  }
  if (t < 64) {
    int c = t * 4, kvh = c >> 6, j = c & 63;
    short4v ov;
#pragma unroll
    for (int u = 0; u < 4; ++u) {
      int jj = j + u;
      float xv = row[1024 + kvh*64 + jj];
      float rot = (jj < 32) ? -row[1024 + kvh*64 + jj + 32] : row[1024 + kvh*64 + jj - 32];
      ov[u] = f2bf(xv * cs[jj & 31] + rot * sn[jj & 31]);
    }
    *(short4v*)&Kb[((size_t)(b*NKV + kvh) * SS + s) * 64 + j] = ov;
  } else if (t < 128) {
    int c = (t - 64) * 4, kvh = c >> 6, j = c & 63;
#pragma unroll
    for (int u = 0; u < 4; ++u)
      Vt[((size_t)(b*NKV + kvh) * 64 + j + u) * SS + s] = f2bf(row[1280 + kvh*64 + j + u]);
  }
}

// ---------------- 128x128 GEMM (single-buffered, proven) --------------------
// EPI: 0 C=v | 1 C=v+R | 6 batched w2: compact rows, atomic scatter |
//      7 batched w13: gather-A by token list, fused SwiGLU -> Cb bf16.
// AFOLD: A k-index folds (k<1024?k:k-1024) for split-precision O-proj.
template<int EPI, int AFOLD>
__global__ __launch_bounds__(256, 2) void gemm_bt(
    const short* __restrict__ A, const short* __restrict__ Bt,
    float* __restrict__ C, short* __restrict__ Cb,
    const float* __restrict__ R,
    const int* __restrict__ idx, const int* __restrict__ meta,
    const float* __restrict__ comb,
    int M, int N, int K, int lda, int ldb) {
  __shared__ short As[128*64];
  __shared__ short Bs[128*64];
  int nx = gridDim.x, ny = gridDim.y;
  int nwg = nx * ny * gridDim.z;
  int o = blockIdx.x + nx * (blockIdx.y + ny * blockIdx.z);
  int xcd = o & 7, loc = o >> 3;
  int q = nwg >> 3, rr = nwg & 7;
  int wg = (xcd < rr ? xcd * (q + 1) : rr * (q + 1) + (xcd - rr) * q) + loc;
  int bm = wg % nx; int t1 = wg / nx; int bn = t1 % ny; int bz = t1 / ny;
  int tid = threadIdx.x;
  int w = tid >> 6, lane = tid & 63;
  int m0 = bm * 128, n0 = bn * 128;
  int cnt = M, abase = 0, eidx = 0, hrow0 = 0;
  const int* list = idx;
  if (EPI == 7) {
    const int* mp = meta + bz * 4;
    cnt = mp[1]; hrow0 = mp[2];
    list = idx + bz * 4096;
    Bt += (size_t)bz * 6144 * ldb;
    if (m0 >= cnt) return;
  }
  if (EPI == 6) {
    eidx = bz >> 1; int slot = bz & 1;
    const int* mp = meta + eidx * 4;
    int cA = mp[0], cT = mp[1];
    cnt = slot ? (cT - cA) : cA;
    abase = mp[2] + (slot ? cA : 0);
    list = idx + eidx * 4096 + (slot ? cA : 0);
    Bt += (size_t)eidx * 1024 * ldb;
    if (m0 >= cnt) return;
  }
  int wr = (w >> 1) * 64, wc = (w & 1) * 64;
  int l15 = lane & 15, lg = lane >> 4;
  int srow = lane >> 3, sslot = lane & 7;
  const short* aptr[4];
  const short* bptr[4];
#pragma unroll
  for (int i = 0; i < 4; ++i) {
    int row = i * 32 + w * 8 + srow;
    int gs = (sslot ^ (row & 7)) * 8;
    int am = m0 + row;
    if (EPI == 7) am = list[am < cnt ? am : cnt - 1];
    else if (EPI == 6) am = abase + am;
    aptr[i] = A + (size_t)am * lda + gs;
    bptr[i] = Bt + (size_t)(n0 + row) * ldb + gs;
  }
  f32x4 acc[4][4] = {};
  int nK = K >> 6;
  for (int kt = 0; kt < nK; ++kt) {
    int k0 = kt << 6;
    int ak0 = AFOLD ? (kt < 16 ? k0 : k0 - 1024) : k0;
    __syncthreads();
#pragma unroll
    for (int i = 0; i < 4; ++i) {
      int r0 = i * 32 + w * 8;
      GLOAD16(aptr[i] + ak0, &As[r0 * 64]);
      GLOAD16(bptr[i] + k0, &Bs[r0 * 64]);
    }
    asm volatile("s_waitcnt vmcnt(0)" ::: "memory");
    __syncthreads();
#pragma unroll
    for (int kh = 0; kh < 2; ++kh) {
      short8 af[4], bfv[4];
#pragma unroll
      for (int mi = 0; mi < 4; ++mi) {
        int row = wr + mi * 16 + l15;
        int sl = (lg + kh * 4) ^ (row & 7);
        af[mi] = *(const short8*)&As[row * 64 + sl * 8];
        int rowb = wc + mi * 16 + l15;
        int slb = (lg + kh * 4) ^ (rowb & 7);
        bfv[mi] = *(const short8*)&Bs[rowb * 64 + slb * 8];
      }
#pragma unroll
      for (int mi = 0; mi < 4; ++mi)
#pragma unroll
        for (int ni = 0; ni < 4; ++ni)
          acc[mi][ni] = mfma16(af[mi], bfv[ni], acc[mi][ni]);
    }
  }
#pragma unroll
  for (int mi = 0; mi < 4; ++mi) {
#pragma unroll
    for (int i = 0; i < 4; ++i) {
      int m = m0 + wr + mi * 16 + 4 * lg + i;
      if (EPI == 7) {
        if (m < cnt) {
          int g0 = (n0 + wc) >> 5;
#pragma unroll
          for (int p = 0; p < 2; ++p) {
            float xg = acc[mi][2*p][i];
            float yg = acc[mi][2*p+1][i];
            float sg = 1.f / (1.f + fexp2(-xg * LOG2E));
            Cb[(size_t)(hrow0 + m) * 3072 + (g0 + p) * 16 + l15] = f2bf(xg * sg * yg);
          }
        }
      } else if (EPI == 6) {
        if (m < cnt) {
          int tok = list[m];
          float wgt = comb[tok * 4 + eidx];
#pragma unroll
          for (int ni = 0; ni < 4; ++ni) {
            int n = n0 + wc + ni * 16 + l15;
            atomicAdd(&C[(size_t)tok * 1024 + n], wgt * acc[mi][ni][i]);
          }
        }
      } else {
#pragma unroll
        for (int ni = 0; ni < 4; ++ni) {
          int n = n0 + wc + ni * 16 + l15;
          size_t cidx = (size_t)m * N + n;
          float v = acc[mi][ni][i];
          if (EPI == 0)      C[cidx] = v;
          else               C[cidx] = v + R[cidx];
        }
      }
    }
  }
}

// ---------------- Flash attention: 8 waves, two q-tiles, LDS K/V ------------
// K/V staged once per block; DOUBLE-BUFFERED with counted-wait 2-phase:
// next tile's global_load_lds issue BEFORE compute, waits AFTER compute
// (raw s_barrier; stage latency hides under QK/exp/PV).
__global__ __launch_bounds__(512) void attn_k(
    const short* __restrict__ Qb, const short* __restrict__ Kb,
    const short* __restrict__ Vt, short* __restrict__ AO2) {
  int id = blockIdx.x;
  int qp = ((id & 15) + ((id >> 8) << 3)) & 15;
  int hb = (id >> 4) & 31;
  int h = hb & 15, b = hb >> 4;
  int tid = threadIdx.x;
  int w = tid >> 6, lane = tid & 63;
  int half = w >> 2, w4 = w & 3;
  int l15 = lane & 15, lg = lane >> 4;
  int kvh = h >> 2;
  __shared__ short Ks[2][64 * 64];
  __shared__ short Vs[2][64 * 64];
  __shared__ short P[8][16 * 72];
  short* Pw = P[w];
  const short* Qp = Qb + (size_t)(b * NH + h) * SS * 64;
  const short* Kp = Kb + (size_t)(b * NKV + kvh) * SS * 64;
  const short* Vp = Vt + (size_t)(b * NKV + kvh) * 64 * SS;
  int qt = half ? (31 - qp) : qp;
  int kmax = 31 - qp;                      // = max(qp, 31-qp) since qp<16
  int qbase = qt * 64 + w4 * 16;
  int qrow0 = qbase + 4 * lg;
  short8 aq0 = *(const short8*)&Qp[(size_t)(qbase + l15) * 64 + 8 * lg];
  short8 aq1 = *(const short8*)&Qp[(size_t)(qbase + l15) * 64 + 8 * lg + 32];
  int srow = lane >> 3, sslot = lane & 7;
  int strow = w * 8 + srow;                // 0..63
  int sgs = (sslot ^ (strow & 7)) * 8;
  const short* ksrc = Kp + (size_t)strow * 64 + sgs;   // += k0*64 per tile
  const short* vsrc = Vp + (size_t)strow * SS + sgs;   // += k0 per tile
  f32x4 o4[4] = {};
  float lst[4] = {0.f, 0.f, 0.f, 0.f};
  // prologue: stage tile 0 into buffer 0
  GLOAD16(ksrc, &Ks[0][(w * 8) * 64]);
  GLOAD16(vsrc, &Vs[0][(w * 8) * 64]);
  asm volatile("s_waitcnt vmcnt(0)" ::: "memory");
  __builtin_amdgcn_s_barrier();
  for (int kt = 0; kt <= kmax; ++kt) {
    int cur = kt & 1;
    if (kt < kmax) {  // issue next tile BEFORE compute (hides under compute)
      int k1 = (kt + 1) * 64;
      GLOAD16(ksrc + (size_t)k1 * 64, &Ks[cur ^ 1][(w * 8) * 64]);
      GLOAD16(vsrc + k1, &Vs[cur ^ 1][(w * 8) * 64]);
    }
    if (kt <= qt) {
      int k0 = kt * 64;
      const short* Kc = &Ks[cur][0];
      const short* Vc = &Vs[cur][0];
      f32x4 sc[4] = {};
      short8 bk[2][4];
#pragma unroll
      for (int kh = 0; kh < 2; ++kh)
#pragma unroll
        for (int ni = 0; ni < 4; ++ni) {
          int row = ni * 16 + l15;
          int sl = (lg + kh * 4) ^ (row & 7);
          bk[kh][ni] = *(const short8*)&Kc[row * 64 + sl * 8];
        }
      __builtin_amdgcn_s_setprio(1);
#pragma unroll
      for (int kh = 0; kh < 2; ++kh)
#pragma unroll
        for (int ni = 0; ni < 4; ++ni)
          sc[ni] = mfma16(kh ? aq1 : aq0, bk[kh][ni], sc[ni]);
      __builtin_amdgcn_s_setprio(0);
      short8 bv[2][4];
#pragma unroll
      for (int kh = 0; kh < 2; ++kh)
#pragma unroll
        for (int di = 0; di < 4; ++di) {
          int row = di * 16 + l15;
          int sl = (lg + kh * 4) ^ (row & 7);
          bv[kh][di] = *(const short8*)&Vc[row * 64 + sl * 8];
        }
      if (kt == qt) {
#pragma unroll
        for (int ni = 0; ni < 4; ++ni)
#pragma unroll
          for (int i = 0; i < 4; ++i)
            if (k0 + ni*16 + l15 > qrow0 + i) sc[ni][i] = -3.0e38f;
      }
#pragma unroll
      for (int i = 0; i < 4; ++i) {
        float ps = 0.f;
#pragma unroll
        for (int ni = 0; ni < 4; ++ni) {
          float pv = fexp2(sc[ni][i]);   // masked -> exp2(-3e38) = +0
          sc[ni][i] = pv;
          ps += pv;
        }
        lst[i] += ps;
      }
#pragma unroll
      for (int ni = 0; ni < 4; ++ni)
#pragma unroll
        for (int i = 0; i < 4; ++i)
          Pw[(4*lg + i) * 72 + ni*16 + l15] = f2bf(sc[ni][i]);
      __builtin_amdgcn_s_setprio(1);
#pragma unroll
      for (int kh = 0; kh < 2; ++kh) {
        short8 ap = *(const short8*)&Pw[l15 * 72 + 8*lg + 32*kh];
#pragma unroll
        for (int di = 0; di < 4; ++di)
          o4[di] = mfma16(ap, bv[kh][di], o4[di]);
      }
      __builtin_amdgcn_s_setprio(0);
    }
    // next-tile loads landed during compute; my LDS reads retired
    asm volatile("s_waitcnt vmcnt(0) lgkmcnt(0)" ::: "memory");
    __builtin_amdgcn_s_barrier();
  }
  float rinv[4];
#pragma unroll
  for (int i = 0; i < 4; ++i) {
    float s = lst[i];
    s += __shfl_xor(s, 1); s += __shfl_xor(s, 2);
    s += __shfl_xor(s, 4); s += __shfl_xor(s, 8);
    rinv[i] = 1.f / s;
  }
#pragma unroll
  for (int di = 0; di < 4; ++di) {
#pragma unroll
    for (int i = 0; i < 4; ++i) {
      float val = o4[di][i] * rinv[i];
      short hi_ = f2bf(val);
      short lo_ = f2bf(val - bf2f(hi_));
      size_t idx = ((size_t)(b * SS + qrow0 + i)) * 2048 + h*64 + di*16 + l15;
      AO2[idx] = hi_;
      AO2[idx + 1024] = lo_;
    }
  }
}

// ------- MoE routing + fused RMSNorm (reads x1 once; writes xn2 + comb) -----
__global__ __launch_bounds__(64) void routing_k(
    const float* __restrict__ x1, const float* __restrict__ g2,
    const float* __restrict__ gate, float* __restrict__ comb,
    int* __restrict__ rsel, short* __restrict__ xn2) {
  int row = blockIdx.x;
  int l = threadIdx.x;
  const float* xr = x1 + (size_t)row * 1024;
  float ss = 0.f;
  float lgt[4] = {0.f, 0.f, 0.f, 0.f};
  for (int it = 0; it < 4; ++it) {
    int d0 = it * 256 + l * 4;
    float4 v = *(const float4*)&xr[d0];
    float4 gv = *(const float4*)&g2[d0];
    const float* vp = (const float*)&v;
    const float* gp = (const float*)&gv;
#pragma unroll
    for (int u = 0; u < 4; ++u) {
      float xv = vp[u];
      ss += xv * xv;
      float xg = xv * gp[u];
      float4 gr = *(const float4*)&gate[(size_t)(d0 + u) * 4];
      lgt[0] += xg * gr.x; lgt[1] += xg * gr.y;
      lgt[2] += xg * gr.z; lgt[3] += xg * gr.w;
    }
  }
#pragma unroll
  for (int off = 1; off < 64; off <<= 1) {
    ss += __shfl_xor(ss, off);
#pragma unroll
    for (int e = 0; e < 4; ++e) lgt[e] += __shfl_xor(lgt[e], off);
  }
  float scn = rsqrtf(ss * (1.f/1024.f) + EPSF);
  for (int it = 0; it < 4; ++it) {
    int d0 = it * 256 + l * 4;
    float4 v = *(const float4*)&xr[d0];
    float4 gv = *(const float4*)&g2[d0];
    short4v ov;
    ov[0] = f2bf(v.x * scn * gv.x);
    ov[1] = f2bf(v.y * scn * gv.y);
    ov[2] = f2bf(v.z * scn * gv.z);
    ov[3] = f2bf(v.w * scn * gv.w);
    *(short4v*)&xn2[(size_t)row * 1024 + d0] = ov;
  }
  if (l == 0) {
    float lmax = fmaxf(fmaxf(lgt[0], lgt[1]), fmaxf(lgt[2], lgt[3]));
    float p[4];
#pragma unroll
    for (int e = 0; e < 4; ++e) p[e] = expf(scn * (lgt[e] - lmax));
    int i1 = 0;
    for (int e = 1; e < 4; ++e) if (p[e] > p[i1]) i1 = e;
    int i2 = (i1 == 0) ? 1 : 0;
    for (int e = 0; e < 4; ++e) if (e != i1 && p[e] > p[i2]) i2 = e;
    float wsum = p[i1] + p[i2];
    float4 ov = {0.f, 0.f, 0.f, 0.f};
    ((float*)&ov)[i1] = p[i1] / wsum;
    ((float*)&ov)[i2] = p[i2] / wsum;
    *(float4*)&comb[(size_t)row * 4] = ov;
    rsel[row] = i1 * 4 + i2;
  }
}

// ---- compaction, all experts in ONE block (fused expert-offset prefix) -----
__global__ __launch_bounds__(1024) void compact_k(
    const int* __restrict__ rsel, int* __restrict__ idxb, int* __restrict__ meta) {
  int t = threadIdx.x;
  int lane = t & 63, wid = t >> 6;
  int base = t * 4;
  int r[4];
#pragma unroll
  for (int j = 0; j < 4; ++j) r[j] = rsel[base + j];
  __shared__ int wsum[16], woff[16], shA, shT;
  int run = 0;
  for (int e = 0; e < 4; ++e) {
    int outb = e * 4096;
#pragma unroll
    for (int pass = 0; pass < 2; ++pass) {
      int loc[4], c = 0;
#pragma unroll
      for (int j = 0; j < 4; ++j) {
        int sel = pass ? (r[j] & 3) : (r[j] >> 2);
        loc[j] = (sel == e) ? 1 : 0;
        c += loc[j];
      }
      int v = c;
#pragma unroll
      for (int off = 1; off < 64; off <<= 1) {
        int o = __shfl_up(v, off);
        if (lane >= off) v += o;
      }
      if (lane == 63) wsum[wid] = v;
      __syncthreads();
      if (t < 16) {
        int s = wsum[t];
        int vv = s;
#pragma unroll
        for (int off = 1; off < 16; off <<= 1) {
          int o = __shfl_up(vv, off);
          if (t >= off) vv += o;
        }
        woff[t] = vv - s;
        if (t == 15) { if (pass == 0) shA = vv; else shT = shA + vv; }
      }
      __syncthreads();
      int pbase = (pass ? shA : 0) + woff[wid] + (v - c);
#pragma unroll
      for (int j = 0; j < 4; ++j)
        if (loc[j]) idxb[outb + pbase++] = base + j;
      __syncthreads();
    }
    if (t == 0) { meta[e*4+0] = shA; meta[e*4+1] = shT; meta[e*4+2] = run; }
    run += shT;
    __syncthreads();
  }
}

// ---------------- launch ----------------------------------------------------
extern "C" void kernel_launch(void* const* d_in, const int* in_sizes, int n_in,
                              void* d_out, int out_size, void* d_ws, size_t ws_size,
                              hipStream_t stream) {
  const float* x    = (const float*)d_in[0];
  const float* g1   = (const float*)d_in[1];
  const float* g2   = (const float*)d_in[2];
  const float* wq   = (const float*)d_in[3];
  const float* wk   = (const float*)d_in[4];
  const float* wv   = (const float*)d_in[5];
  const float* wo   = (const float*)d_in[6];
  const float* gate = (const float*)d_in[7];
  const float* w1   = (const float*)d_in[8];
  const float* w2   = (const float*)d_in[9];
  const float* w3   = (const float*)d_in[10];
  float* out = (float*)d_out;

  char* p = (char*)d_ws;
  size_t off = 0;
  auto carve = [&](size_t bytes) {
    void* r = p + off;
    off = (off + bytes + 255) & ~(size_t)255;
    return r;
  };
  short* wqkvT = (short*)carve((size_t)1536 * 1024 * 2);
  short* woC3  = (short*)carve((size_t)1024 * 3072 * 2);
  short* w13T  = (short*)carve((size_t)NEXP * 6144 * 1024 * 2);
  short* w2T   = (short*)carve((size_t)NEXP * 1024 * 3072 * 2);
  short* xn1   = (short*)carve((size_t)NT * DIMD * 2);
  short* xn2   = (short*)carve((size_t)NT * DIMD * 2);
  float* qkv   = (float*)carve((size_t)NT * 1536 * 4);
  float* cosT  = (float*)carve((size_t)SS * 32 * 4);
  float* sinT  = (float*)carve((size_t)SS * 32 * 4);
  short* Qb    = (short*)carve((size_t)BB * NH * SS * HD * 2);
  short* Kb    = (short*)carve((size_t)BB * NKV * SS * HD * 2);
  short* Vt    = (short*)carve((size_t)BB * NKV * HD * SS * 2);
  short* AO2   = (short*)carve((size_t)NT * 2048 * 2);
  float* comb  = (float*)carve((size_t)NT * 4 * 4);
  int*   rsel  = (int*)carve((size_t)NT * 4);
  int*   idxb  = (int*)carve((size_t)NEXP * 4096 * 4);
  int*   meta  = (int*)carve((size_t)16 * 4);
  short* Hb    = (short*)carve((size_t)(2 * NT + 256) * 3072 * 2);
  (void)ws_size; (void)in_sizes; (void)n_in; (void)out_size;

  dim3 blk(256);
  // unified prep: all transposes + rope tables + rmsnorm1 in ONE dispatch
  prep_k<<<dim3(14464), blk, 0, stream>>>(wq, wk, wv, wo, w1, w3, w2, x, g1,
      wqkvT, woC3, w13T, w2T, cosT, sinT, xn1);

  // attention
  gemm_bt<0,0><<<dim3(32, 12), blk, 0, stream>>>(xn1, wqkvT, qkv, (short*)0, (const float*)0,
      (const int*)0, (const int*)0, (const float*)0, NT, 1536, 1024, 1024, 1024);
  rope_scatter_k<<<dim3(NT), blk, 0, stream>>>(qkv, cosT, sinT, Qb, Kb, Vt);
  attn_k<<<dim3(512), dim3(512), 0, stream>>>(Qb, Kb, Vt, AO2);
  // O-projection split precision in ONE GEMM: K=3072, A=[hi|hi|lo] via fold,
  // B=[Whi|Wlo|Whi]; +x residual.
  gemm_bt<1,1><<<dim3(32, 8), blk, 0, stream>>>(AO2, woC3, out, (short*)0, x,
      (const int*)0, (const int*)0, (const float*)0, NT, 1024, 3072, 2048, 3072);

  // MoE (routing kernel also writes xn2 = RMSNorm(out)*g2)
  routing_k<<<dim3(NT), dim3(64), 0, stream>>>(out, g2, gate, comb, rsel, xn2);
  compact_k<<<dim3(1), dim3(1024), 0, stream>>>(rsel, idxb, meta);
  // all experts in one dispatch: 128^2 gather-GEMM + fused SwiGLU -> Hb
  gemm_bt<7,0><<<dim3(32, 48, 4), blk, 0, stream>>>(xn2, w13T, (float*)0, Hb, (const float*)0,
      idxb, meta, (const float*)0, NT, 6144, 1024, 1024, 1024);
  // w2 scatter-accumulate, both slots in one dispatch (atomicAdd f32)
  gemm_bt<6,0><<<dim3(32, 8, 8), blk, 0, stream>>>(Hb, w2T, out, (short*)0, (const float*)0,
      idxb, meta, comb, NT, 1024, 3072, 3072, 3072);
}

// Round 11
// 438.918 us; speedup vs baseline: 1.4446x; 1.0159x over previous
//
#include <hip/hip_runtime.h>
#include <stdint.h>

#define DIMD 1024
#define NH 16
#define NKV 4
#define HD 64
#define NEXP 4
#define HID 3072
#define BB 2
#define SS 2048
#define NT (BB*SS)
#define EPSF 1.1920928955078125e-07f
#define LOG2E 1.4426950408889634f
#define QSCALE 0.18033688011112042f

typedef short short8 __attribute__((ext_vector_type(8)));
typedef short short4v __attribute__((ext_vector_type(4)));
typedef float f32x4 __attribute__((ext_vector_type(4)));

__device__ __forceinline__ short f2bf(float f) {
  union { float f; unsigned u; } c; c.f = f;
  unsigned u = c.u;
  unsigned r = u + 0x7fffu + ((u >> 16) & 1u);
  return (short)(r >> 16);
}
__device__ __forceinline__ float bf2f(short s) {
  union { unsigned u; float f; } c;
  c.u = ((unsigned)(unsigned short)s) << 16;
  return c.f;
}
__device__ __forceinline__ float fexp2(float x) {
#if __has_builtin(__builtin_amdgcn_exp2f)
  return __builtin_amdgcn_exp2f(x);
#else
  return exp2f(x);
#endif
}

__device__ __forceinline__ f32x4 mfma16(short8 a, short8 b, f32x4 c) {
  return __builtin_amdgcn_mfma_f32_16x16x32_bf16(a, b, c, 0, 0, 0);
}

#define GLOAD16(gp, lp) __builtin_amdgcn_global_load_lds( \
    (const __attribute__((address_space(1))) void*)(gp),  \
    (__attribute__((address_space(3))) void*)(lp), 16, 0, 0)

// ======== unified prep: ALL weight transposes + rope tables + rmsnorm1 ======
__global__ __launch_bounds__(256) void prep_k(
    const float* __restrict__ wq, const float* __restrict__ wk,
    const float* __restrict__ wv, const float* __restrict__ wo,
    const float* __restrict__ w1, const float* __restrict__ w3,
    const float* __restrict__ w2,
    const float* __restrict__ x, const float* __restrict__ g1,
    short* __restrict__ wqkvT, short* __restrict__ woC3,
    short* __restrict__ w13T, short* __restrict__ w2T,
    float* __restrict__ cosT, float* __restrict__ sinT,
    short* __restrict__ xn1) {
  __shared__ float tile[64][68];
  int id = blockIdx.x;
  int t = threadIdx.x;
  if (id < 10112) {
    const float* in; short* o1; short* o2 = (short*)0;
    int split = 0, N, ldo1, ldo2 = 0, mm = 0, bx, by;
    if (id < 256)      { in = wq; o1 = wqkvT; N = 1024; ldo1 = 1024; bx = id % 16; by = id / 16; }
    else if (id < 320) { int r = id - 256; in = wk; o1 = wqkvT + (size_t)1024 * 1024; N = 256; ldo1 = 1024; bx = r % 4; by = r / 4; }
    else if (id < 384) { int r = id - 320; in = wv; o1 = wqkvT + (size_t)1280 * 1024; N = 256; ldo1 = 1024; bx = r % 4; by = r / 4; }
    else if (id < 640) { int r = id - 384; in = wo; o1 = woC3; o2 = woC3 + 1024; split = 1; N = 1024; ldo1 = 3072; ldo2 = 3072; bx = r % 16; by = r / 16; }
    else if (id < 896) { int r = id - 640; in = wo; o1 = woC3 + 2048; N = 1024; ldo1 = 3072; bx = r % 16; by = r / 16; }
    else if (id < 3968) { int r = id - 896; int bz = r / 768; int rr = r % 768;
      in = w1 + (size_t)bz * 1024 * 3072; o1 = w13T + (size_t)bz * 6144 * 1024;
      N = 3072; ldo1 = 1024; mm = 1; bx = rr % 48; by = rr / 48; }
    else if (id < 7040) { int r = id - 3968; int bz = r / 768; int rr = r % 768;
      in = w3 + (size_t)bz * 1024 * 3072; o1 = w13T + (size_t)bz * 6144 * 1024;
      N = 3072; ldo1 = 1024; mm = 2; bx = rr % 48; by = rr / 48; }
    else { int r = id - 7040; int bz = r / 768; int rr = r % 768;
      in = w2 + (size_t)bz * 3072 * 1024; o1 = w2T + (size_t)bz * 1024 * 3072;
      N = 1024; ldo1 = 3072; bx = rr % 16; by = rr / 16; }
    int tx = t & 15, ty = t >> 4;
    int n0 = bx * 64, k0 = by * 64;
#pragma unroll
    for (int p = 0; p < 4; ++p) {
      int k = p * 16 + ty;
      *(float4*)&tile[k][tx * 4] = *(const float4*)&in[(size_t)(k0 + k) * N + n0 + tx * 4];
    }
    __syncthreads();
#pragma unroll
    for (int p = 0; p < 4; ++p) {
      int n = n0 + p * 16 + ty;
      int np = mm ? ((n >> 4) * 32 + (n & 15) + ((mm == 2) ? 16 : 0)) : n;
      int k4 = tx * 4;
      short4v hv, lv;
#pragma unroll
      for (int j = 0; j < 4; ++j) {
        float v = tile[k4 + j][p * 16 + ty];
        short h_ = f2bf(v);
        hv[j] = h_;
        if (split) lv[j] = f2bf(v - bf2f(h_));
      }
      *(short4v*)&o1[(size_t)np * ldo1 + k0 + k4] = hv;
      if (split) *(short4v*)&o2[(size_t)np * ldo2 + k0 + k4] = lv;
    }
  } else if (id < 10368) {
    int tt = (id - 10112) * 256 + t;      // 2048*32 entries
    int s = tt >> 5, i = tt & 31;
    float invf = powf(10000.0f, -(float)i / 32.0f);
    float a = (float)s * invf;
    cosT[tt] = cosf(a);
    sinT[tt] = sinf(a);
  } else {
    int row = id - 10368;
    const float4* xr = (const float4*)(x + (size_t)row * DIMD);
    float4 v = xr[t];
    float ss = v.x*v.x + v.y*v.y + v.z*v.z + v.w*v.w;
#pragma unroll
    for (int off = 1; off < 64; off <<= 1) ss += __shfl_xor(ss, off);
    float* red = (float*)tile;
    if ((t & 63) == 0) red[t >> 6] = ss;
    __syncthreads();
    float tot = red[0] + red[1] + red[2] + red[3];
    float scn = rsqrtf(tot * (1.f/1024.f) + EPSF);
    float4 gv = ((const float4*)g1)[t];
    short4v ov;
    ov[0] = f2bf(v.x * scn * gv.x);
    ov[1] = f2bf(v.y * scn * gv.y);
    ov[2] = f2bf(v.z * scn * gv.z);
    ov[3] = f2bf(v.w * scn * gv.w);
    ((short4v*)xn1)[(size_t)row * 256 + t] = ov;
  }
}

// ---------------- 128x128 GEMM (single-buffered, proven) --------------------
// EPI: 0 C=v | 1 C=v+R | 2 fused RoPE+scatter QKV epilogue |
//      6 batched w2: compact rows, atomic scatter |
//      7 batched w13: gather-A by token list, fused SwiGLU -> Cb bf16.
// AFOLD: A k-index folds (k<1024?k:k-1024) for split-precision O-proj.
template<int EPI, int AFOLD>
__global__ __launch_bounds__(256, 2) void gemm_bt(
    const short* __restrict__ A, const short* __restrict__ Bt,
    float* __restrict__ C, short* __restrict__ Cb,
    const float* __restrict__ R,
    const int* __restrict__ idx, const int* __restrict__ meta,
    const float* __restrict__ comb,
    int M, int N, int K, int lda, int ldb,
    const float* __restrict__ cosP, const float* __restrict__ sinP,
    short* __restrict__ Qb_, short* __restrict__ Kb_, short* __restrict__ Vt_) {
  __shared__ short As[128*64];
  __shared__ short Bs[128*64];
  int nx = gridDim.x, ny = gridDim.y;
  int nwg = nx * ny * gridDim.z;
  int o = blockIdx.x + nx * (blockIdx.y + ny * blockIdx.z);
  int xcd = o & 7, loc = o >> 3;
  int q = nwg >> 3, rr = nwg & 7;
  int wg = (xcd < rr ? xcd * (q + 1) : rr * (q + 1) + (xcd - rr) * q) + loc;
  int bm = wg % nx; int t1 = wg / nx; int bn = t1 % ny; int bz = t1 / ny;
  int tid = threadIdx.x;
  int w = tid >> 6, lane = tid & 63;
  int m0 = bm * 128, n0 = bn * 128;
  int cnt = M, abase = 0, eidx = 0, hrow0 = 0;
  const int* list = idx;
  if (EPI == 7) {
    const int* mp = meta + bz * 4;
    cnt = mp[1]; hrow0 = mp[2];
    list = idx + bz * 4096;
    Bt += (size_t)bz * 6144 * ldb;
    if (m0 >= cnt) return;
  }
  if (EPI == 6) {
    eidx = bz >> 1; int slot = bz & 1;
    const int* mp = meta + eidx * 4;
    int cA = mp[0], cT = mp[1];
    cnt = slot ? (cT - cA) : cA;
    abase = mp[2] + (slot ? cA : 0);
    list = idx + eidx * 4096 + (slot ? cA : 0);
    Bt += (size_t)eidx * 1024 * ldb;
    if (m0 >= cnt) return;
  }
  int wr = (w >> 1) * 64, wc = (w & 1) * 64;
  int l15 = lane & 15, lg = lane >> 4;
  int srow = lane >> 3, sslot = lane & 7;
  const short* aptr[4];
  const short* bptr[4];
#pragma unroll
  for (int i = 0; i < 4; ++i) {
    int row = i * 32 + w * 8 + srow;
    int gs = (sslot ^ (row & 7)) * 8;
    int am = m0 + row;
    if (EPI == 7) am = list[am < cnt ? am : cnt - 1];
    else if (EPI == 6) am = abase + am;
    aptr[i] = A + (size_t)am * lda + gs;
    bptr[i] = Bt + (size_t)(n0 + row) * ldb + gs;
  }
  f32x4 acc[4][4] = {};
  int nK = K >> 6;
  for (int kt = 0; kt < nK; ++kt) {
    int k0 = kt << 6;
    int ak0 = AFOLD ? (kt < 16 ? k0 : k0 - 1024) : k0;
    __syncthreads();
#pragma unroll
    for (int i = 0; i < 4; ++i) {
      int r0 = i * 32 + w * 8;
      GLOAD16(aptr[i] + ak0, &As[r0 * 64]);
      GLOAD16(bptr[i] + k0, &Bs[r0 * 64]);
    }
    asm volatile("s_waitcnt vmcnt(0)" ::: "memory");
    __syncthreads();
#pragma unroll
    for (int kh = 0; kh < 2; ++kh) {
      short8 af[4], bfv[4];
#pragma unroll
      for (int mi = 0; mi < 4; ++mi) {
        int row = wr + mi * 16 + l15;
        int sl = (lg + kh * 4) ^ (row & 7);
        af[mi] = *(const short8*)&As[row * 64 + sl * 8];
        int rowb = wc + mi * 16 + l15;
        int slb = (lg + kh * 4) ^ (rowb & 7);
        bfv[mi] = *(const short8*)&Bs[rowb * 64 + slb * 8];
      }
#pragma unroll
      for (int mi = 0; mi < 4; ++mi)
#pragma unroll
        for (int ni = 0; ni < 4; ++ni)
          acc[mi][ni] = mfma16(af[mi], bfv[ni], acc[mi][ni]);
    }
  }
#pragma unroll
  for (int mi = 0; mi < 4; ++mi) {
#pragma unroll
    for (int i = 0; i < 4; ++i) {
      int m = m0 + wr + mi * 16 + 4 * lg + i;
      if (EPI == 2) {
        // fused RoPE + scatter to Qb/Kb/Vt. Thread's 4 n-cols within one
        // 64-wide head are {0,16,32,48}+l15 -> rotate-half pair = ni^2.
        int bb = m >> 11, s = m & 2047;
        int nb = n0 + wc;
        float v0 = acc[mi][0][i], v1 = acc[mi][1][i];
        float v2 = acc[mi][2][i], v3 = acc[mi][3][i];
        if (nb < 1280) {
          float c0 = cosP[s*32 + l15], c1 = cosP[s*32 + 16 + l15];
          float s0 = sinP[s*32 + l15], s1 = sinP[s*32 + 16 + l15];
          float r0 = v0*c0 - v2*s0, r2 = v2*c0 + v0*s0;
          float r1 = v1*c1 - v3*s1, r3 = v3*c1 + v1*s1;
          if (nb < 1024) {
            int h = nb >> 6;
            size_t base = ((size_t)(bb*16 + h) * 2048 + s) * 64 + l15;
            Qb_[base]      = f2bf(r0 * QSCALE);
            Qb_[base + 16] = f2bf(r1 * QSCALE);
            Qb_[base + 32] = f2bf(r2 * QSCALE);
            Qb_[base + 48] = f2bf(r3 * QSCALE);
          } else {
            int kvh = (nb - 1024) >> 6;
            size_t base = ((size_t)(bb*4 + kvh) * 2048 + s) * 64 + l15;
            Kb_[base]      = f2bf(r0);
            Kb_[base + 16] = f2bf(r1);
            Kb_[base + 32] = f2bf(r2);
            Kb_[base + 48] = f2bf(r3);
          }
        } else {
          int kvh = (nb - 1280) >> 6;
          size_t base = ((size_t)(bb*4 + kvh) * 64 + l15) * 2048 + s;
          Vt_[base]           = f2bf(v0);
          Vt_[base + 16*2048] = f2bf(v1);
          Vt_[base + 32*2048] = f2bf(v2);
          Vt_[base + 48*2048] = f2bf(v3);
        }
      } else if (EPI == 7) {
        if (m < cnt) {
          int g0 = (n0 + wc) >> 5;
#pragma unroll
          for (int p = 0; p < 2; ++p) {
            float xg = acc[mi][2*p][i];
            float yg = acc[mi][2*p+1][i];
            float sg = 1.f / (1.f + fexp2(-xg * LOG2E));
            Cb[(size_t)(hrow0 + m) * 3072 + (g0 + p) * 16 + l15] = f2bf(xg * sg * yg);
          }
        }
      } else if (EPI == 6) {
        if (m < cnt) {
          int tok = list[m];
          float wgt = comb[tok * 4 + eidx];
#pragma unroll
          for (int ni = 0; ni < 4; ++ni) {
            int n = n0 + wc + ni * 16 + l15;
            atomicAdd(&C[(size_t)tok * 1024 + n], wgt * acc[mi][ni][i]);
          }
        }
      } else {
#pragma unroll
        for (int ni = 0; ni < 4; ++ni) {
          int n = n0 + wc + ni * 16 + l15;
          size_t cidx = (size_t)m * N + n;
          float v = acc[mi][ni][i];
          if (EPI == 0)      C[cidx] = v;
          else               C[cidx] = v + R[cidx];
        }
      }
    }
  }
}

// ---------------- Flash attention: 8 waves, two q-tiles, LDS K/V ------------
__global__ __launch_bounds__(512) void attn_k(
    const short* __restrict__ Qb, const short* __restrict__ Kb,
    const short* __restrict__ Vt, short* __restrict__ AO2) {
  int id = blockIdx.x;
  int qp = ((id & 15) + ((id >> 8) << 3)) & 15;
  int hb = (id >> 4) & 31;
  int h = hb & 15, b = hb >> 4;
  int tid = threadIdx.x;
  int w = tid >> 6, lane = tid & 63;
  int half = w >> 2, w4 = w & 3;
  int l15 = lane & 15, lg = lane >> 4;
  int kvh = h >> 2;
  __shared__ short Ks[2][64 * 64];
  __shared__ short Vs[2][64 * 64];
  __shared__ short P[8][16 * 72];
  short* Pw = P[w];
  const short* Qp = Qb + (size_t)(b * NH + h) * SS * 64;
  const short* Kp = Kb + (size_t)(b * NKV + kvh) * SS * 64;
  const short* Vp = Vt + (size_t)(b * NKV + kvh) * 64 * SS;
  int qt = half ? (31 - qp) : qp;
  int kmax = 31 - qp;
  int qbase = qt * 64 + w4 * 16;
  int qrow0 = qbase + 4 * lg;
  short8 aq0 = *(const short8*)&Qp[(size_t)(qbase + l15) * 64 + 8 * lg];
  short8 aq1 = *(const short8*)&Qp[(size_t)(qbase + l15) * 64 + 8 * lg + 32];
  int srow = lane >> 3, sslot = lane & 7;
  int strow = w * 8 + srow;
  int sgs = (sslot ^ (strow & 7)) * 8;
  const short* ksrc = Kp + (size_t)strow * 64 + sgs;
  const short* vsrc = Vp + (size_t)strow * SS + sgs;
  f32x4 o4[4] = {};
  float lst[4] = {0.f, 0.f, 0.f, 0.f};
  GLOAD16(ksrc, &Ks[0][(w * 8) * 64]);
  GLOAD16(vsrc, &Vs[0][(w * 8) * 64]);
  asm volatile("s_waitcnt vmcnt(0)" ::: "memory");
  __builtin_amdgcn_s_barrier();
  for (int kt = 0; kt <= kmax; ++kt) {
    int cur = kt & 1;
    if (kt < kmax) {
      int k1 = (kt + 1) * 64;
      GLOAD16(ksrc + (size_t)k1 * 64, &Ks[cur ^ 1][(w * 8) * 64]);
      GLOAD16(vsrc + k1, &Vs[cur ^ 1][(w * 8) * 64]);
    }
    if (kt <= qt) {
      int k0 = kt * 64;
      const short* Kc = &Ks[cur][0];
      const short* Vc = &Vs[cur][0];
      f32x4 sc[4] = {};
      short8 bk[2][4];
#pragma unroll
      for (int kh = 0; kh < 2; ++kh)
#pragma unroll
        for (int ni = 0; ni < 4; ++ni) {
          int row = ni * 16 + l15;
          int sl = (lg + kh * 4) ^ (row & 7);
          bk[kh][ni] = *(const short8*)&Kc[row * 64 + sl * 8];
        }
      __builtin_amdgcn_s_setprio(1);
#pragma unroll
      for (int kh = 0; kh < 2; ++kh)
#pragma unroll
        for (int ni = 0; ni < 4; ++ni)
          sc[ni] = mfma16(kh ? aq1 : aq0, bk[kh][ni], sc[ni]);
      __builtin_amdgcn_s_setprio(0);
      short8 bv[2][4];
#pragma unroll
      for (int kh = 0; kh < 2; ++kh)
#pragma unroll
        for (int di = 0; di < 4; ++di) {
          int row = di * 16 + l15;
          int sl = (lg + kh * 4) ^ (row & 7);
          bv[kh][di] = *(const short8*)&Vc[row * 64 + sl * 8];
        }
      if (kt == qt) {
#pragma unroll
        for (int ni = 0; ni < 4; ++ni)
#pragma unroll
          for (int i = 0; i < 4; ++i)
            if (k0 + ni*16 + l15 > qrow0 + i) sc[ni][i] = -3.0e38f;
      }
#pragma unroll
      for (int i = 0; i < 4; ++i) {
        float ps = 0.f;
#pragma unroll
        for (int ni = 0; ni < 4; ++ni) {
          float pv = fexp2(sc[ni][i]);
          sc[ni][i] = pv;
          ps += pv;
        }
        lst[i] += ps;
      }
#pragma unroll
      for (int ni = 0; ni < 4; ++ni)
#pragma unroll
        for (int i = 0; i < 4; ++i)
          Pw[(4*lg + i) * 72 + ni*16 + l15] = f2bf(sc[ni][i]);
      __builtin_amdgcn_s_setprio(1);
#pragma unroll
      for (int kh = 0; kh < 2; ++kh) {
        short8 ap = *(const short8*)&Pw[l15 * 72 + 8*lg + 32*kh];
#pragma unroll
        for (int di = 0; di < 4; ++di)
          o4[di] = mfma16(ap, bv[kh][di], o4[di]);
      }
      __builtin_amdgcn_s_setprio(0);
    }
    asm volatile("s_waitcnt vmcnt(0) lgkmcnt(0)" ::: "memory");
    __builtin_amdgcn_s_barrier();
  }
  float rinv[4];
#pragma unroll
  for (int i = 0; i < 4; ++i) {
    float s = lst[i];
    s += __shfl_xor(s, 1); s += __shfl_xor(s, 2);
    s += __shfl_xor(s, 4); s += __shfl_xor(s, 8);
    rinv[i] = 1.f / s;
  }
#pragma unroll
  for (int di = 0; di < 4; ++di) {
#pragma unroll
    for (int i = 0; i < 4; ++i) {
      float val = o4[di][i] * rinv[i];
      short hi_ = f2bf(val);
      short lo_ = f2bf(val - bf2f(hi_));
      size_t idx = ((size_t)(b * SS + qrow0 + i)) * 2048 + h*64 + di*16 + l15;
      AO2[idx] = hi_;
      AO2[idx + 1024] = lo_;
    }
  }
}

// ------- MoE routing + fused RMSNorm; 4 wave-rows per block -----------------
__global__ __launch_bounds__(256) void routing_k(
    const float* __restrict__ x1, const float* __restrict__ g2,
    const float* __restrict__ gate, float* __restrict__ comb,
    int* __restrict__ rsel, short* __restrict__ xn2) {
  int row = blockIdx.x * 4 + (threadIdx.x >> 6);
  int l = threadIdx.x & 63;
  const float* xr = x1 + (size_t)row * 1024;
  float ss = 0.f;
  float lgt[4] = {0.f, 0.f, 0.f, 0.f};
  for (int it = 0; it < 4; ++it) {
    int d0 = it * 256 + l * 4;
    float4 v = *(const float4*)&xr[d0];
    float4 gv = *(const float4*)&g2[d0];
    const float* vp = (const float*)&v;
    const float* gp = (const float*)&gv;
#pragma unroll
    for (int u = 0; u < 4; ++u) {
      float xv = vp[u];
      ss += xv * xv;
      float xg = xv * gp[u];
      float4 gr = *(const float4*)&gate[(size_t)(d0 + u) * 4];
      lgt[0] += xg * gr.x; lgt[1] += xg * gr.y;
      lgt[2] += xg * gr.z; lgt[3] += xg * gr.w;
    }
  }
#pragma unroll
  for (int off = 1; off < 64; off <<= 1) {
    ss += __shfl_xor(ss, off);
#pragma unroll
    for (int e = 0; e < 4; ++e) lgt[e] += __shfl_xor(lgt[e], off);
  }
  float scn = rsqrtf(ss * (1.f/1024.f) + EPSF);
  for (int it = 0; it < 4; ++it) {
    int d0 = it * 256 + l * 4;
    float4 v = *(const float4*)&xr[d0];
    float4 gv = *(const float4*)&g2[d0];
    short4v ov;
    ov[0] = f2bf(v.x * scn * gv.x);
    ov[1] = f2bf(v.y * scn * gv.y);
    ov[2] = f2bf(v.z * scn * gv.z);
    ov[3] = f2bf(v.w * scn * gv.w);
    *(short4v*)&xn2[(size_t)row * 1024 + d0] = ov;
  }
  if (l == 0) {
    float lmax = fmaxf(fmaxf(lgt[0], lgt[1]), fmaxf(lgt[2], lgt[3]));
    float p[4];
#pragma unroll
    for (int e = 0; e < 4; ++e) p[e] = expf(scn * (lgt[e] - lmax));
    int i1 = 0;
    for (int e = 1; e < 4; ++e) if (p[e] > p[i1]) i1 = e;
    int i2 = (i1 == 0) ? 1 : 0;
    for (int e = 0; e < 4; ++e) if (e != i1 && p[e] > p[i2]) i2 = e;
    float wsum = p[i1] + p[i2];
    float4 ov = {0.f, 0.f, 0.f, 0.f};
    ((float*)&ov)[i1] = p[i1] / wsum;
    ((float*)&ov)[i2] = p[i2] / wsum;
    *(float4*)&comb[(size_t)row * 4] = ov;
    rsel[row] = i1 * 4 + i2;
  }
}

// ---- compaction, all experts in ONE block (fused expert-offset prefix) -----
__global__ __launch_bounds__(1024) void compact_k(
    const int* __restrict__ rsel, int* __restrict__ idxb, int* __restrict__ meta) {
  int t = threadIdx.x;
  int lane = t & 63, wid = t >> 6;
  int base = t * 4;
  int r[4];
#pragma unroll
  for (int j = 0; j < 4; ++j) r[j] = rsel[base + j];
  __shared__ int wsum[16], woff[16], shA, shT;
  int run = 0;
  for (int e = 0; e < 4; ++e) {
    int outb = e * 4096;
#pragma unroll
    for (int pass = 0; pass < 2; ++pass) {
      int loc[4], c = 0;
#pragma unroll
      for (int j = 0; j < 4; ++j) {
        int sel = pass ? (r[j] & 3) : (r[j] >> 2);
        loc[j] = (sel == e) ? 1 : 0;
        c += loc[j];
      }
      int v = c;
#pragma unroll
      for (int off = 1; off < 64; off <<= 1) {
        int o = __shfl_up(v, off);
        if (lane >= off) v += o;
      }
      if (lane == 63) wsum[wid] = v;
      __syncthreads();
      if (t < 16) {
        int s = wsum[t];
        int vv = s;
#pragma unroll
        for (int off = 1; off < 16; off <<= 1) {
          int o = __shfl_up(vv, off);
          if (t >= off) vv += o;
        }
        woff[t] = vv - s;
        if (t == 15) { if (pass == 0) shA = vv; else shT = shA + vv; }
      }
      __syncthreads();
      int pbase = (pass ? shA : 0) + woff[wid] + (v - c);
#pragma unroll
      for (int j = 0; j < 4; ++j)
        if (loc[j]) idxb[outb + pbase++] = base + j;
      __syncthreads();
    }
    if (t == 0) { meta[e*4+0] = shA; meta[e*4+1] = shT; meta[e*4+2] = run; }
    run += shT;
    __syncthreads();
  }
}

// ---------------- launch ----------------------------------------------------
extern "C" void kernel_launch(void* const* d_in, const int* in_sizes, int n_in,
                              void* d_out, int out_size, void* d_ws, size_t ws_size,
                              hipStream_t stream) {
  const float* x    = (const float*)d_in[0];
  const float* g1   = (const float*)d_in[1];
  const float* g2   = (const float*)d_in[2];
  const float* wq   = (const float*)d_in[3];
  const float* wk   = (const float*)d_in[4];
  const float* wv   = (const float*)d_in[5];
  const float* wo   = (const float*)d_in[6];
  const float* gate = (const float*)d_in[7];
  const float* w1   = (const float*)d_in[8];
  const float* w2   = (const float*)d_in[9];
  const float* w3   = (const float*)d_in[10];
  float* out = (float*)d_out;

  char* p = (char*)d_ws;
  size_t off = 0;
  auto carve = [&](size_t bytes) {
    void* r = p + off;
    off = (off + bytes + 255) & ~(size_t)255;
    return r;
  };
  short* wqkvT = (short*)carve((size_t)1536 * 1024 * 2);
  short* woC3  = (short*)carve((size_t)1024 * 3072 * 2);
  short* w13T  = (short*)carve((size_t)NEXP * 6144 * 1024 * 2);
  short* w2T   = (short*)carve((size_t)NEXP * 1024 * 3072 * 2);
  short* xn1   = (short*)carve((size_t)NT * DIMD * 2);
  short* xn2   = (short*)carve((size_t)NT * DIMD * 2);
  float* cosT  = (float*)carve((size_t)SS * 32 * 4);
  float* sinT  = (float*)carve((size_t)SS * 32 * 4);
  short* Qb    = (short*)carve((size_t)BB * NH * SS * HD * 2);
  short* Kb    = (short*)carve((size_t)BB * NKV * SS * HD * 2);
  short* Vt    = (short*)carve((size_t)BB * NKV * HD * SS * 2);
  short* AO2   = (short*)carve((size_t)NT * 2048 * 2);
  float* comb  = (float*)carve((size_t)NT * 4 * 4);
  int*   rsel  = (int*)carve((size_t)NT * 4);
  int*   idxb  = (int*)carve((size_t)NEXP * 4096 * 4);
  int*   meta  = (int*)carve((size_t)16 * 4);
  short* Hb    = (short*)carve((size_t)(2 * NT + 256) * 3072 * 2);
  (void)ws_size; (void)in_sizes; (void)n_in; (void)out_size;

  dim3 blk(256);
  // unified prep: all transposes + rope tables + rmsnorm1 in ONE dispatch
  prep_k<<<dim3(14464), blk, 0, stream>>>(wq, wk, wv, wo, w1, w3, w2, x, g1,
      wqkvT, woC3, w13T, w2T, cosT, sinT, xn1);

  // attention: QKV GEMM with fused RoPE+scatter epilogue (no qkv intermediate)
  gemm_bt<2,0><<<dim3(32, 12), blk, 0, stream>>>(xn1, wqkvT, (float*)0, (short*)0, (const float*)0,
      (const int*)0, (const int*)0, (const float*)0, NT, 1536, 1024, 1024, 1024,
      cosT, sinT, Qb, Kb, Vt);
  attn_k<<<dim3(512), dim3(512), 0, stream>>>(Qb, Kb, Vt, AO2);
  // O-projection split precision in ONE GEMM: K=3072, A=[hi|hi|lo] via fold,
  // B=[Whi|Wlo|Whi]; +x residual.
  gemm_bt<1,1><<<dim3(32, 8), blk, 0, stream>>>(AO2, woC3, out, (short*)0, x,
      (const int*)0, (const int*)0, (const float*)0, NT, 1024, 3072, 2048, 3072,
      (const float*)0, (const float*)0, (short*)0, (short*)0, (short*)0);

  // MoE (routing kernel also writes xn2 = RMSNorm(out)*g2)
  routing_k<<<dim3(NT/4), blk, 0, stream>>>(out, g2, gate, comb, rsel, xn2);
  compact_k<<<dim3(1), dim3(1024), 0, stream>>>(rsel, idxb, meta);
  // all experts in one dispatch: 128^2 gather-GEMM + fused SwiGLU -> Hb
  gemm_bt<7,0><<<dim3(32, 48, 4), blk, 0, stream>>>(xn2, w13T, (float*)0, Hb, (const float*)0,
      idxb, meta, (const float*)0, NT, 6144, 1024, 1024, 1024,
      (const float*)0, (const float*)0, (short*)0, (short*)0, (short*)0);
  // w2 scatter-accumulate, both slots in one dispatch (atomicAdd f32)
  gemm_bt<6,0><<<dim3(32, 8, 8), blk, 0, stream>>>(Hb, w2T, out, (short*)0, (const float*)0,
      idxb, meta, comb, NT, 1024, 3072, 3072, 3072,
      (const float*)0, (const float*)0, (short*)0, (short*)0, (short*)0);
}